// Round 9
// baseline (341.727 us; speedup 1.0000x reference)
//
#include <hip/hip_runtime.h>

// ---------------- constants ----------------
#define BB 2
#define SEQ 4096
#define LQ 4064
#define HID 1024
#define NH 16
#define HD 64
#define NB 64      // number of 64-wide blocks in sequence
#define BLK 64
#define NR 3
#define PENV -10000.0f

typedef __bf16 bf16;
typedef __bf16 bf16x8 __attribute__((ext_vector_type(8)));
typedef float floatx4 __attribute__((ext_vector_type(4)));

#define MEMFENCE asm volatile("" ::: "memory")

__device__ inline floatx4 mfma16(bf16x8 a, bf16x8 b, floatx4 c) {
    return __builtin_amdgcn_mfma_f32_16x16x32_bf16(a, b, c, 0, 0, 0);
}

// async global->LDS, 16B per lane (global_load_lds_dwordx4)
__device__ inline void async_ld16(const bf16* g, bf16* l) {
    __builtin_amdgcn_global_load_lds(
        (const __attribute__((address_space(1))) unsigned int*)g,
        (__attribute__((address_space(3))) unsigned int*)l, 16, 0, 0);
}

// stage 2 K blocks (8KB each) into LDS dst (linear), source pre-swizzled so that
// LDS[row][c16] = G[row][c16 ^ (row&7)]  (c16 = 16B column within 128B row).
// 4 async_ld16 per thread.
__device__ inline void stage_k2(const bf16* kkbh, bf16* dst, int kb0, int kb1, int tid) {
    #pragma unroll
    for (int it = 0; it < 2; it++) {
        int o = (it * 256 + tid) * 16;            // byte offset within an 8KB block
        int row = o >> 7;
        int c16 = (o >> 4) & 7;
        int srcel = row * 64 + ((c16 ^ (row & 7)) << 3);   // element offset, swizzled source
        async_ld16(kkbh + (size_t)kb0 * (BLK * HD) + srcel, dst + (o >> 1));
        async_ld16(kkbh + (size_t)kb1 * (BLK * HD) + srcel, dst + 4096 + (o >> 1));
    }
}

// ---------------- prep: pad + cast X to bf16 ----------------
__global__ __launch_bounds__(256) void cast_pad_x(const float* __restrict__ X,
                                                  bf16* __restrict__ Xp) {
    int t = blockIdx.x * 256 + threadIdx.x;
    int c4 = t & 255;
    int row = t >> 8;
    int b = row >> 12;
    int s = row & 4095;
    float4 v = make_float4(0.f, 0.f, 0.f, 0.f);
    if (s < LQ) {
        v = reinterpret_cast<const float4*>(X + ((size_t)(b * LQ + s)) * HID)[c4];
    }
    union { bf16 h[4]; uint2 u; } o;
    o.h[0] = (bf16)v.x; o.h[1] = (bf16)v.y; o.h[2] = (bf16)v.z; o.h[3] = (bf16)v.w;
    *reinterpret_cast<uint2*>(Xp + (size_t)row * HID + c4 * 4) = o.u;
}

// ---------------- prep: transpose + cast weights ----------------
__global__ __launch_bounds__(256) void transpose_w(const float* __restrict__ Wq,
                                                   const float* __restrict__ Wk,
                                                   const float* __restrict__ Wv,
                                                   const float* __restrict__ Wo,
                                                   bf16* __restrict__ WqkvT,
                                                   bf16* __restrict__ WoT) {
    __shared__ float tile[64][65];
    int sel = blockIdx.z;
    const float* src = (sel == 0) ? Wq : (sel == 1) ? Wk : (sel == 2) ? Wv : Wo;
    bf16* dst = (sel < 3) ? (WqkvT + (size_t)sel * HID * HID) : WoT;
    int j0 = blockIdx.x * 64, k0 = blockIdx.y * 64;
    int tx = threadIdx.x, ty = threadIdx.y;   // (64,4)
    for (int i = 0; i < 16; i++) {
        int k = ty + i * 4;
        tile[k][tx] = src[(size_t)(k0 + k) * HID + j0 + tx];
    }
    __syncthreads();
    for (int i = 0; i < 16; i++) {
        int j = ty + i * 4;
        dst[(size_t)(j0 + j) * HID + k0 + tx] = (bf16)tile[tx][j];
    }
}

// ---------------- prep: transpose band mask ----------------
// band[b][l][q=64][k=192] -> bandT[b][l][k=192][q=64]
__global__ __launch_bounds__(256) void transpose_band(const float* __restrict__ band,
                                                      float* __restrict__ bandT) {
    __shared__ float tile[64][65];
    int kt = blockIdx.x;           // 0..2
    int lrow = blockIdx.y;         // 0..59
    int b = blockIdx.z;
    const float* src = band + ((size_t)(b * (NB - 4) + lrow) * BLK) * 192;
    float* dst = bandT + ((size_t)(b * (NB - 4) + lrow) * 192) * BLK;
    int tx = threadIdx.x, ty = threadIdx.y;   // (64,4)
    for (int i = 0; i < 16; i++) {
        int qq = i * 4 + ty;
        tile[qq][tx] = src[(size_t)qq * 192 + kt * 64 + tx];
    }
    __syncthreads();
    for (int i = 0; i < 16; i++) {
        int k = i * 4 + ty;
        dst[(size_t)(kt * 64 + k) * BLK + tx] = tile[tx][k];
    }
}

// ---------------- prep: mask violation flags (parallel) ----------------
__global__ __launch_bounds__(256) void mask_viol(const float* __restrict__ tom,
                                                 const float* __restrict__ blocked,
                                                 const float* __restrict__ band,
                                                 int* __restrict__ flags) {
    int which = blockIdx.y, b = blockIdx.z;
    const float* src;
    size_t n;
    if (which == 0)      { src = tom     + (size_t)b * SEQ;                  n = SEQ; }
    else if (which == 1) { src = blocked + (size_t)b * NB * BLK;             n = NB * BLK; }
    else                 { src = band    + (size_t)b * (NB - 4) * BLK * 192; n = (size_t)(NB - 4) * BLK * 192; }
    const float4* s4 = (const float4*)src;
    size_t n4 = n >> 2;
    int bad = 0;
    for (size_t i = blockIdx.x * 256 + threadIdx.x; i < n4; i += 240 * 256) {
        float4 v = s4[i];
        bad |= (v.x != 1.0f) | (v.y != 1.0f) | (v.z != 1.0f) | (v.w != 1.0f);
    }
    if (__any(bad) && (threadIdx.x & 63) == 0)
        atomicOr(&flags[which * BB + b], 1);
}

// ---------------- GEMM1: QKV projection ----------------
__global__ __launch_bounds__(256) void gemm_qkv(const bf16* __restrict__ Xp,
                                                const bf16* __restrict__ WT,
                                                const float* __restrict__ bq,
                                                const float* __restrict__ bk,
                                                const float* __restrict__ bv,
                                                bf16* __restrict__ qo,
                                                bf16* __restrict__ ko,
                                                bf16* __restrict__ vt) {
    __shared__ __align__(16) char smem[36864];   // staging 32KB; epi 4x9216B overlays
    bf16* As = (bf16*)smem;            // [128][64]
    bf16* Bs = As + 128 * 64;          // [128][64]
    int tid = threadIdx.x;
    int wave = tid >> 6, lane = tid & 63;
    int quad = lane >> 4, lm = lane & 15;
    int id = blockIdx.x;
    int xcd = id & 7, slot = id >> 3;
    int tile_m = (xcd * 8 + (slot & 7)) * 128;   // 64 tile_m rows across 8 XCDs
    int tile_n = (slot >> 3) * 128;              // 24 tile_n cols
    int wm = (wave & 1) * 64, wn = (wave >> 1) * 64;

    floatx4 acc[4][4] = {};

    for (int k0 = 0; k0 < HID; k0 += 64) {
        __syncthreads();
        for (int it = 0; it < 4; it++) {
            int c = it * 256 + tid;           // LDS offset = c*16B (lane-contig)
            int row = c >> 3, col = (c & 7) * 8;
            async_ld16(Xp + (size_t)(tile_m + row) * HID + k0 + col, &As[c * 8]);
            async_ld16(WT + (size_t)(tile_n + row) * HID + k0 + col, &Bs[c * 8]);
        }
        __syncthreads();
        for (int ks = 0; ks < 64; ks += 32) {
            bf16x8 a[4], b[4];
            for (int i = 0; i < 4; i++)
                a[i] = *reinterpret_cast<const bf16x8*>(&As[(wm + i * 16 + lm) * 64 + ks + quad * 8]);
            for (int j = 0; j < 4; j++)
                b[j] = *reinterpret_cast<const bf16x8*>(&Bs[(wn + j * 16 + lm) * 64 + ks + quad * 8]);
            for (int i = 0; i < 4; i++)
                for (int j = 0; j < 4; j++)
                    acc[i][j] = mfma16(a[i], b[j], acc[i][j]);
        }
    }

    int which = tile_n >> 10;                 // 0=q,1=k,2=v (wave-uniform)
    int hc_base = (tile_n + wn) & 1023;       // multiple of 64
    int h = hc_base >> 6;
    const float* bias = (which == 0) ? bq : (which == 1) ? bk : bv;
    __syncthreads();                          // retire all staging reads before overlay
    bf16* ep = (bf16*)smem + wave * (64 * 72);

    if (which < 2) {
        #pragma unroll
        for (int i = 0; i < 4; i++)
            #pragma unroll
            for (int j = 0; j < 4; j++) {
                float bsv = bias[hc_base + j * 16 + lm];
                #pragma unroll
                for (int r = 0; r < 4; r++) {
                    float val = acc[i][j][r] + bsv;
                    if (which == 0) val *= 0.125f;
                    ep[(i * 16 + quad * 4 + r) * 72 + j * 16 + lm] = (bf16)val;
                }
            }
        __builtin_amdgcn_wave_barrier();
        int s_glob = tile_m + wm + lane;
        int b_ = s_glob >> 12, s = s_glob & 4095;
        bf16* dstb = ((which == 0) ? qo : ko) + ((size_t)((b_ * NH + h) * SEQ + s)) * HD;
        #pragma unroll
        for (int c = 0; c < 8; c++)
            *reinterpret_cast<uint4*>(dstb + c * 8) =
                *reinterpret_cast<const uint4*>(ep + lane * 72 + c * 8);
    } else {
        #pragma unroll
        for (int i = 0; i < 4; i++)
            #pragma unroll
            for (int j = 0; j < 4; j++) {
                float bsv = bias[hc_base + j * 16 + lm];
                #pragma unroll
                for (int r = 0; r < 4; r++) {
                    float val = acc[i][j][r] + bsv;
                    ep[(j * 16 + lm) * 72 + i * 16 + quad * 4 + r] = (bf16)val;
                }
            }
        __builtin_amdgcn_wave_barrier();
        int s_base = tile_m + wm;
        int b_ = s_base >> 12, s0 = s_base & 4095;
        bf16* dstb = vt + ((size_t)((b_ * NH + h) * HD + lane)) * SEQ + s0;
        #pragma unroll
        for (int c = 0; c < 8; c++)
            *reinterpret_cast<uint4*>(dstb + c * 8) =
                *reinterpret_cast<const uint4*>(ep + lane * 72 + c * 8);
    }
}

// ---------------- attention ----------------
// grid: (B*NH, 70). blockIdx.x = bh -> XCD-resident K/V per (b,h) (XCD = bh%8).
// Round-8 structure (110.9us) + IN-REGISTER P TRANSPOSE:
//   sc[u][f][r] (S^T: key=f*16+quad*4+r, q=lm) -> PV B-operand
//   (P[key=quad*8+j][q=lm]) is a 4-quad redistribution at fixed lm:
//   target quad q takes pk[u][f=q>>1 (+2 for hi half)] from source lanes
//   quad_s = 2(q&1) and 2(q&1)+1. Done with 16 shfl + selects per u --
//   NO LDS P buffer, NO wave barriers, pipelined DS-permute latency.
//   Frees 17.4KB LDS: block footprint 50176 -> 32768 (4-5 blocks/CU).
// y<8: full rows (l=0/63), sub=y&3, register-path K, LDS combine (overlays
//   the staging region, which fullmode never writes).
// y>=8: middle row l=y-7, sub=wave; K staged via DMA into double-buffered
//   swizzled LDS; counted vmcnt (8 mid, 16 last) keeps vf0/staged-K in flight.
__global__ __launch_bounds__(256, 2) void attn_kernel(const bf16* __restrict__ q,
                                                      const bf16* __restrict__ kk,
                                                      const bf16* __restrict__ vt,
                                                      const float* __restrict__ bandT,
                                                      const float* __restrict__ fromm,
                                                      const float* __restrict__ tom,
                                                      const float* __restrict__ blocked,
                                                      const int* __restrict__ rand_attn,
                                                      const int* __restrict__ flags,
                                                      bf16* __restrict__ attn) {
    // [0,32768): K staging, 2 buffers x (2 blocks x 4096 elems).
    // Fullmode: combine overlay (ctxL 16KB + mL/lL 512B) -- staging unused there.
    __shared__ __align__(16) char smem[32768];
    bf16* sK = (bf16*)smem;

    int tid = threadIdx.x, wave = tid >> 6, lane = tid & 63;
    int quad = lane >> 4, lm = lane & 15;
    int sw = lm & 7;                        // K-swizzle row key ((f*16+lm)&7 == lm&7)
    int bh = blockIdx.x;
    int b = bh >> 4, h = bh & 15;
    size_t bh_base = (size_t)bh * SEQ * HD;
    int x = blockIdx.y;
    bool fullmode = (x < 8);
    int l, sub;
    if (fullmode) { l = (x >> 2) ? (NB - 1) : 0; sub = x & 3; }
    else          { l = x - 7;                   sub = wave;  }

    bool do_to = flags[b] != 0;          // to_mask has non-ones
    bool do_bl = flags[BB + b] != 0;     // blocked has non-ones
    bool do_bd = flags[2 * BB + b] != 0; // band has non-ones

    // key-block list (middle mode), packed: kbp = 8 x 6-bit block ids (byte lanes),
    // typ_p = 8 x 4-bit types. type: 0=to_mask, 1..3=band(t), 4=rand, 5=pad.
    unsigned long long kbp = 0ull;
    unsigned int typ_p = 0u;
    if (!fullmode) {
        int base;
        if (l == 1) {
            kbp = (1ull << 8) | (2ull << 16) | ((unsigned long long)(NB - 1) << 24);
            base = 4;
        } else if (l == NB - 2) {
            kbp = ((unsigned long long)(NB - 3) << 8) | ((unsigned long long)(NB - 2) << 16) |
                  ((unsigned long long)(NB - 1) << 24);
            base = 4;
        } else {
            kbp = ((unsigned long long)(l - 1) << 8) | ((unsigned long long)l << 16) |
                  ((unsigned long long)(l + 1) << 24) | ((unsigned long long)(NB - 1) << 32);
            typ_p = (1u << 4) | (2u << 8) | (3u << 12);
            base = 5;
        }
        const int* ra = rand_attn + ((size_t)(b * NH + h) * (NB - 2) + (l - 1)) * NR;
        #pragma unroll
        for (int r = 0; r < NR; r++) {
            int rv = __builtin_amdgcn_readfirstlane(ra[r]);
            kbp   |= (unsigned long long)(rv & 63) << ((base + r) * 8);
            typ_p |= 4u << ((base + r) * 4);
        }
        for (int i = base + NR; i < 8; i++) typ_p |= 5u << (i * 4);   // pads (kb=0, masked off)
    }

    // Q fragments + per-lane query mask (issued before staging so the c0 wait
    // retires them together with the prologue stage; latencies overlap).
    bf16x8 aq0 = *reinterpret_cast<const bf16x8*>(
        q + bh_base + (size_t)(l * BLK + sub * 16 + lm) * HD + quad * 8);
    bf16x8 aq1 = *reinterpret_cast<const bf16x8*>(
        q + bh_base + (size_t)(l * BLK + sub * 16 + lm) * HD + 32 + quad * 8);
    float mq = blocked[((size_t)b * NB + l) * BLK + sub * 16 + lm];

    if (!fullmode) {
        MEMFENCE;
        int a0 = (int)((kbp >> 0) & 63),  a1 = (int)((kbp >> 8) & 63);
        int b0 = (int)((kbp >> 16) & 63), b1 = (int)((kbp >> 24) & 63);
        stage_k2(kk + bh_base, sK + 0,    a0, a1, tid);
        stage_k2(kk + bh_base, sK + 8192, b0, b1, tid);
        MEMFENCE;
    }

    floatx4 ctx[4] = {};        // O^T: d=dj*16+quad*4+r, query=lm
    float mrun = -1e30f, lrun = 0.f;   // lrun: PER-LANE partial (reduced at end)

    int sbase = ((quad & 1) << 5) + lm;   // source lane pair base for P shuffle
    int fhi = quad >> 1;                  // f-register select for P shuffle

    int nch = fullmode ? 8 : 4;
    for (int ch = 0; ch < nch; ch++) {
        int i0 = ch * 2, i1 = i0 + 1;
        int kb0, kb1, ty0, ty1;
        if (fullmode) {
            kb0 = __builtin_amdgcn_readfirstlane(wave * 16 + i0);
            kb1 = kb0 + 1;
            ty0 = 0; ty1 = 0;
        } else {
            kb0 = __builtin_amdgcn_readfirstlane((int)((kbp >> (i0 * 8)) & 63));
            kb1 = __builtin_amdgcn_readfirstlane((int)((kbp >> (i1 * 8)) & 63));
            ty0 = (int)((typ_p >> (i0 * 4)) & 15);
            ty1 = (int)((typ_p >> (i1 * 4)) & 15);
        }

        // ---- vf0 issue FIRST (addresses independent of K) ----
        const bf16* v0p = vt + bh_base + (size_t)kb0 * BLK;
        bf16x8 vf0[4][2];
        #pragma unroll
        for (int dj = 0; dj < 4; dj++) {
            vf0[dj][0] = *reinterpret_cast<const bf16x8*>(v0p + (size_t)(dj * 16 + lm) * SEQ + quad * 8);
            vf0[dj][1] = *reinterpret_cast<const bf16x8*>(v0p + (size_t)(dj * 16 + lm) * SEQ + 32 + quad * 8);
        }
        MEMFENCE;

        // ---- scores: S^T = K * Q^T; sc[u][f][r] = S^T[key=f*16+quad*4+r][q=lm] ----
        floatx4 sc[2][4];
        if (!fullmode) {
            // own stage (issued last chunk / prologue) retired; vf0 kept in flight
            if (ch < 3) asm volatile("s_waitcnt vmcnt(8)" ::: "memory");
            else        asm volatile("s_waitcnt vmcnt(16)" ::: "memory");  // stage(8) only
            __builtin_amdgcn_s_barrier();
            const bf16* kbuf = sK + (ch & 1) * 8192;
            #pragma unroll
            for (int u = 0; u < 2; u++) {
                bf16x8 ka[4], kb_[4];
                #pragma unroll
                for (int f = 0; f < 4; f++) {
                    int rowb = (f * 16 + lm) * 64;
                    ka[f]  = *reinterpret_cast<const bf16x8*>(
                        kbuf + u * 4096 + rowb + ((quad ^ sw) << 3));
                    kb_[f] = *reinterpret_cast<const bf16x8*>(
                        kbuf + u * 4096 + rowb + (((quad | 4) ^ sw) << 3));
                }
                #pragma unroll
                for (int f = 0; f < 4; f++) {
                    floatx4 z = {0.f, 0.f, 0.f, 0.f};
                    z = mfma16(ka[f], aq0, z);
                    z = mfma16(kb_[f], aq1, z);
                    sc[u][f] = z;
                }
            }
        } else {
            const bf16* k0p = kk + bh_base + (size_t)kb0 * (BLK * HD);
            const bf16* k1p = kk + bh_base + (size_t)kb1 * (BLK * HD);
            bf16x8 kfa[2][4], kfb[2][4];
            #pragma unroll
            for (int f = 0; f < 4; f++) {
                kfa[0][f] = *reinterpret_cast<const bf16x8*>(k0p + (f * 16 + lm) * HD + quad * 8);
                kfb[0][f] = *reinterpret_cast<const bf16x8*>(k0p + (f * 16 + lm) * HD + 32 + quad * 8);
                kfa[1][f] = *reinterpret_cast<const bf16x8*>(k1p + (f * 16 + lm) * HD + quad * 8);
                kfb[1][f] = *reinterpret_cast<const bf16x8*>(k1p + (f * 16 + lm) * HD + 32 + quad * 8);
            }
            #pragma unroll
            for (int u = 0; u < 2; u++)
                #pragma unroll
                for (int f = 0; f < 4; f++) {
                    floatx4 z = {0.f, 0.f, 0.f, 0.f};
                    z = mfma16(kfa[u][f], aq0, z);
                    z = mfma16(kfb[u][f], aq1, z);
                    sc[u][f] = z;
                }
        }

        // ---- vf1 issue (after QK so K frags are dead; ~600cy before PV1 use) ----
        const bf16* v1p = vt + bh_base + (size_t)kb1 * BLK;
        bf16x8 vf1[4][2];
        #pragma unroll
        for (int dj = 0; dj < 4; dj++) {
            vf1[dj][0] = *reinterpret_cast<const bf16x8*>(v1p + (size_t)(dj * 16 + lm) * SEQ + quad * 8);
            vf1[dj][1] = *reinterpret_cast<const bf16x8*>(v1p + (size_t)(dj * 16 + lm) * SEQ + 32 + quad * 8);
        }
        MEMFENCE;

        // ---- masks (key = f*16+quad*4+r, query = lm); skipped when mask all-ones ----
        {
            int kbs[2] = {kb0, kb1};
            int tys[2] = {ty0, ty1};
            #pragma unroll
            for (int u = 0; u < 2; u++) {
                int kb = kbs[u], typ = tys[u];
                if (typ == 0) {
                    if (do_to) {
                        #pragma unroll
                        for (int f = 0; f < 4; f++) {
                            float4 t4 = *reinterpret_cast<const float4*>(
                                tom + (size_t)b * SEQ + kb * BLK + f * 16 + quad * 4);
                            sc[u][f][0] += (1.f - t4.x) * PENV;
                            sc[u][f][1] += (1.f - t4.y) * PENV;
                            sc[u][f][2] += (1.f - t4.z) * PENV;
                            sc[u][f][3] += (1.f - t4.w) * PENV;
                        }
                    }
                } else if (typ == 4) {
                    if (do_bl) {
                        #pragma unroll
                        for (int f = 0; f < 4; f++) {
                            float4 t4 = *reinterpret_cast<const float4*>(
                                blocked + ((size_t)b * NB + kb) * BLK + f * 16 + quad * 4);
                            sc[u][f][0] += (1.f - mq * t4.x) * PENV;
                            sc[u][f][1] += (1.f - mq * t4.y) * PENV;
                            sc[u][f][2] += (1.f - mq * t4.z) * PENV;
                            sc[u][f][3] += (1.f - mq * t4.w) * PENV;
                        }
                    }
                } else if (typ != 5) {
                    if (do_bd) {
                        int t = typ - 1;
                        const float* bp = bandT + ((size_t)(b * (NB - 4) + (l - 2)) * 192 + t * 64) * BLK;
                        #pragma unroll
                        for (int f = 0; f < 4; f++)
                            #pragma unroll
                            for (int r = 0; r < 4; r++) {
                                float bm = bp[(size_t)(f * 16 + quad * 4 + r) * BLK + sub * 16 + lm];
                                sc[u][f][r] += (1.f - bm) * PENV;
                            }
                    }
                } else {
                    #pragma unroll
                    for (int f = 0; f < 4; f++)
                        #pragma unroll
                        for (int r = 0; r < 4; r++) sc[u][f][r] += PENV;
                }
            }
        }

        // ---- softmax: chunk max via 3 PARALLEL shuffles (one DS latency) ----
        float mx = -1e30f;
        #pragma unroll
        for (int u = 0; u < 2; u++)
            #pragma unroll
            for (int f = 0; f < 4; f++)
                #pragma unroll
                for (int r = 0; r < 4; r++) mx = fmaxf(mx, sc[u][f][r]);
        float a16 = __shfl_xor(mx, 16, 64);
        float a32 = __shfl_xor(mx, 32, 64);
        float a48 = __shfl_xor(mx, 48, 64);
        mx = fmaxf(fmaxf(mx, a16), fmaxf(a32, a48));
        float mnew = fmaxf(mrun, mx);
        float scale = __expf(mrun - mnew);
        #pragma unroll
        for (int dj = 0; dj < 4; dj++) ctx[dj] *= scale;
        mrun = mnew;

        // ---- exp -> packed bf16 pairs (in register); per-lane partial row-sum ----
        float rs = 0.f;
        uint2 pk[2][4];
        #pragma unroll
        for (int u = 0; u < 2; u++)
            #pragma unroll
            for (int f = 0; f < 4; f++) {
                float p0 = __expf(sc[u][f][0] - mnew);
                float p1 = __expf(sc[u][f][1] - mnew);
                float p2 = __expf(sc[u][f][2] - mnew);
                float p3 = __expf(sc[u][f][3] - mnew);
                rs += (p0 + p1) + (p2 + p3);
                union { bf16 hh[4]; uint2 u2; } pu;
                pu.hh[0] = (bf16)p0; pu.hh[1] = (bf16)p1;
                pu.hh[2] = (bf16)p2; pu.hh[3] = (bf16)p3;
                pk[u][f] = pu.u2;
            }
        lrun = lrun * scale + rs;          // per-lane partial; reduced once at end

        // ---- in-register P transpose: sc layout -> PV B-operand layout ----
        // target quad q: pb[u][0] = pk[u][q>>1]   from lanes (2(q&1))*16+lm, +16
        //                pb[u][1] = pk[u][2+q>>1] from the same lane pair
        bf16x8 pb[2][2];
        #pragma unroll
        for (int u = 0; u < 2; u++) {
            unsigned g0x[4], g0y[4], g1x[4], g1y[4];
            #pragma unroll
            for (int f = 0; f < 4; f++) {
                g0x[f] = (unsigned)__shfl((int)pk[u][f].x, sbase, 64);
                g0y[f] = (unsigned)__shfl((int)pk[u][f].y, sbase, 64);
                g1x[f] = (unsigned)__shfl((int)pk[u][f].x, sbase + 16, 64);
                g1y[f] = (unsigned)__shfl((int)pk[u][f].y, sbase + 16, 64);
            }
            union { unsigned v[4]; bf16x8 hv; } lo, hi;
            lo.v[0] = fhi ? g0x[1] : g0x[0];
            lo.v[1] = fhi ? g0y[1] : g0y[0];
            lo.v[2] = fhi ? g1x[1] : g1x[0];
            lo.v[3] = fhi ? g1y[1] : g1y[0];
            hi.v[0] = fhi ? g0x[3] : g0x[2];
            hi.v[1] = fhi ? g0y[3] : g0y[2];
            hi.v[2] = fhi ? g1x[3] : g1x[2];
            hi.v[3] = fhi ? g1y[3] : g1y[2];
            pb[u][0] = lo.hv;
            pb[u][1] = hi.hv;
        }

        // ---- stage chunk ch+1's K (ISSUED LAST so PV waits never drain it) ----
        if (!fullmode && ch >= 1 && ch + 1 < 4) {
            int na = __builtin_amdgcn_readfirstlane((int)((kbp >> ((ch + 1) * 16)) & 63));
            int nb = __builtin_amdgcn_readfirstlane((int)((kbp >> ((ch + 1) * 16 + 8)) & 63));
            stage_k2(kk + bh_base, sK + ((ch + 1) & 1) * 8192, na, nb, tid);
            MEMFENCE;
        }

        // ---- PV block 0 (auto-wait vmcnt keeps vf1 + staged K in flight) ----
        #pragma unroll
        for (int dj = 0; dj < 4; dj++) {
            ctx[dj] = mfma16(vf0[dj][0], pb[0][0], ctx[dj]);
            ctx[dj] = mfma16(vf0[dj][1], pb[0][1], ctx[dj]);
        }
        // ---- PV block 1 (auto-wait keeps staged K in flight) ----
        #pragma unroll
        for (int dj = 0; dj < 4; dj++) {
            ctx[dj] = mfma16(vf1[dj][0], pb[1][0], ctx[dj]);
            ctx[dj] = mfma16(vf1[dj][1], pb[1][1], ctx[dj]);
        }
    }

    // ---- deferred l-sum reduce: 3 parallel shuffles, once per kernel ----
    {
        float b16 = __shfl_xor(lrun, 16, 64);
        float b32 = __shfl_xor(lrun, 32, 64);
        float b48 = __shfl_xor(lrun, 48, 64);
        lrun = (lrun + b16) + (b32 + b48);
    }

    if (!fullmode) {
        // per-lane finalize: query = lm
        int sq = l * BLK + sub * 16 + lm;
        float w = (1.f / lrun) * fromm[(size_t)b * SEQ + sq];
        bf16* dst = attn + ((size_t)(b * SEQ + sq)) * HID + h * HD;
        #pragma unroll
        for (int dj = 0; dj < 4; dj++) {
            union { bf16 hh[4]; uint2 u2; } o;
            #pragma unroll
            for (int r = 0; r < 4; r++) o.hh[r] = (bf16)(ctx[dj][r] * w);
            *reinterpret_cast<uint2*>(dst + dj * 16 + quad * 4) = o.u2;
        }
    } else {
        // cross-wave combine (4 partials over the same 16 queries)
        float* ctxL = (float*)smem;                    // [wave][d=64][q=16] (staging region, free)
        float* mL   = (float*)(smem + 16384);          // [wave][16]
        float* lL   = (float*)(smem + 16640);          // [wave][16]
        __syncthreads();
        #pragma unroll
        for (int dj = 0; dj < 4; dj++)
            #pragma unroll
            for (int r = 0; r < 4; r++)
                ctxL[wave * 1024 + (dj * 16 + quad * 4 + r) * 16 + lm] = ctx[dj][r];
        if (quad == 0) { mL[wave * 16 + lm] = mrun; lL[wave * 16 + lm] = lrun; }
        __syncthreads();
        int qq = tid & 15, dbase = (tid >> 4) * 4;
        float M = -1e30f;
        for (int w = 0; w < 4; w++) M = fmaxf(M, mL[w * 16 + qq]);
        float e[4], Lt = 0.f;
        for (int w = 0; w < 4; w++) { e[w] = __expf(mL[w * 16 + qq] - M); Lt += lL[w * 16 + qq] * e[w]; }
        int sq = l * BLK + sub * 16 + qq;
        float wgt = (1.f / Lt) * fromm[(size_t)b * SEQ + sq];
        union { bf16 hh[4]; uint2 u2; } o;
        #pragma unroll
        for (int dd = 0; dd < 4; dd++) {
            float acc = 0.f;
            for (int w = 0; w < 4; w++) acc += ctxL[w * 1024 + (dbase + dd) * 16 + qq] * e[w];
            o.hh[dd] = (bf16)(acc * wgt);
        }
        *reinterpret_cast<uint2*>(attn + ((size_t)(b * SEQ + sq)) * HID + h * HD + dbase) = o.u2;
    }
}

// ---------------- GEMM2: output projection ----------------
__global__ __launch_bounds__(256) void gemm_out(const bf16* __restrict__ A,
                                                const bf16* __restrict__ WoT,
                                                const float* __restrict__ bo,
                                                float* __restrict__ out) {
    __shared__ __align__(16) bf16 As[128 * 64];
    __shared__ __align__(16) bf16 Bs[128 * 64];
    int tid = threadIdx.x;
    int wave = tid >> 6, lane = tid & 63;
    int quad = lane >> 4, lm = lane & 15;
    int id = blockIdx.x;
    int xcd = id & 7, slot = id >> 3;
    int tile_m = (xcd * 8 + (slot & 7)) * 128;
    int tile_n = (slot >> 3) * 128;
    int wm = (wave & 1) * 64, wn = (wave >> 1) * 64;

    floatx4 acc[4][4] = {};

    for (int k0 = 0; k0 < HID; k0 += 64) {
        __syncthreads();
        for (int it = 0; it < 4; it++) {
            int c = it * 256 + tid;
            int row = c >> 3, col = (c & 7) * 8;
            async_ld16(A + (size_t)(tile_m + row) * HID + k0 + col, &As[c * 8]);
            async_ld16(WoT + (size_t)(tile_n + row) * HID + k0 + col, &Bs[c * 8]);
        }
        __syncthreads();
        for (int ks = 0; ks < 64; ks += 32) {
            bf16x8 a[4], b[4];
            for (int i = 0; i < 4; i++)
                a[i] = *reinterpret_cast<const bf16x8*>(&As[(wm + i * 16 + lm) * 64 + ks + quad * 8]);
            for (int j = 0; j < 4; j++)
                b[j] = *reinterpret_cast<const bf16x8*>(&Bs[(wn + j * 16 + lm) * 64 + ks + quad * 8]);
            for (int i = 0; i < 4; i++)
                for (int j = 0; j < 4; j++)
                    acc[i][j] = mfma16(a[i], b[j], acc[i][j]);
        }
    }

    for (int i = 0; i < 4; i++) {
        for (int j = 0; j < 4; j++) {
            int nn = tile_n + wn + j * 16 + lm;
            float bsv = bo[nn];
            for (int r = 0; r < 4; r++) {
                int mm = tile_m + wm + i * 16 + quad * 4 + r;
                int b_ = mm >> 12, s = mm & 4095;
                if (s < LQ)
                    out[((size_t)(b_ * LQ + s)) * HID + nn] = acc[i][j][r] + bsv;
            }
        }
    }
}

// ---------------- launcher ----------------
extern "C" void kernel_launch(void* const* d_in, const int* in_sizes, int n_in,
                              void* d_out, int out_size, void* d_ws, size_t ws_size,
                              hipStream_t stream) {
    const float* X       = (const float*)d_in[0];
    const float* Wq      = (const float*)d_in[1];
    const float* bq      = (const float*)d_in[2];
    const float* Wk      = (const float*)d_in[3];
    const float* bk      = (const float*)d_in[4];
    const float* Wv      = (const float*)d_in[5];
    const float* bv      = (const float*)d_in[6];
    const float* Wo      = (const float*)d_in[7];
    const float* bo      = (const float*)d_in[8];
    const float* band    = (const float*)d_in[9];
    const float* fromm   = (const float*)d_in[10];
    const float* tom     = (const float*)d_in[11];
    const float* blocked = (const float*)d_in[12];
    const int*   randa   = (const int*)d_in[13];
    float* out = (float*)d_out;

    char* ws = (char*)d_ws;
    bf16* Xp    = (bf16*)(ws + 0);              // 16,777,216 B (reused as attn)
    bf16* WqkvT = (bf16*)(ws + 16777216);       //  6,291,456 B (reused as bandT+flags after gemm_qkv)
    bf16* WoT   = (bf16*)(ws + 23068672);       //  2,097,152 B
    bf16* qb    = (bf16*)(ws + 25165824);       // 16,777,216 B
    bf16* kb    = (bf16*)(ws + 41943040);       // 16,777,216 B
    bf16* vtb   = (bf16*)(ws + 58720256);       // 16,777,216 B (d-major V)
    bf16* attnb = Xp;                           // Xp dead after gemm_qkv
    float* bandT = (float*)WqkvT;               // 5,898,240 B, alive only during attn
    int* flagsp = (int*)(ws + 16777216 + 5898240);  // 24 B, inside dead WqkvT tail

    cast_pad_x<<<dim3(8192), dim3(256), 0, stream>>>(X, Xp);
    transpose_w<<<dim3(16, 16, 4), dim3(64, 4), 0, stream>>>(Wq, Wk, Wv, Wo, WqkvT, WoT);
    gemm_qkv<<<dim3(1536), dim3(256), 0, stream>>>(Xp, WqkvT, bq, bk, bv, qb, kb, vtb);
    transpose_band<<<dim3(3, NB - 4, BB), dim3(64, 4), 0, stream>>>(band, bandT);
    hipMemsetAsync(flagsp, 0, 3 * BB * sizeof(int), stream);
    mask_viol<<<dim3(240, 3, BB), dim3(256), 0, stream>>>(tom, blocked, band, flagsp);
    attn_kernel<<<dim3(BB * NH, 70), dim3(256), 0, stream>>>(qb, kb, vtb, bandT, fromm, tom,
                                                             blocked, randa, flagsp, attnb);
    gemm_out<<<dim3(512), dim3(256), 0, stream>>>(attnb, WoT, bo, out);
}

// Round 10
// 334.064 us; speedup vs baseline: 1.0229x; 1.0229x over previous
//
#include <hip/hip_runtime.h>

// ---------------- constants ----------------
#define BB 2
#define SEQ 4096
#define LQ 4064
#define HID 1024
#define NH 16
#define HD 64
#define NB 64      // number of 64-wide blocks in sequence
#define BLK 64
#define NR 3
#define PENV -10000.0f

typedef __bf16 bf16;
typedef __bf16 bf16x8 __attribute__((ext_vector_type(8)));
typedef float floatx4 __attribute__((ext_vector_type(4)));

#define MEMFENCE asm volatile("" ::: "memory")

__device__ inline floatx4 mfma16(bf16x8 a, bf16x8 b, floatx4 c) {
    return __builtin_amdgcn_mfma_f32_16x16x32_bf16(a, b, c, 0, 0, 0);
}

// async global->LDS, 16B per lane (global_load_lds_dwordx4)
__device__ inline void async_ld16(const bf16* g, bf16* l) {
    __builtin_amdgcn_global_load_lds(
        (const __attribute__((address_space(1))) unsigned int*)g,
        (__attribute__((address_space(3))) unsigned int*)l, 16, 0, 0);
}

// stage 2 K blocks (8KB each) into LDS dst (linear), source pre-swizzled so that
// LDS[row][c16] = G[row][c16 ^ (row&7)]  (c16 = 16B column within 128B row).
// 4 async_ld16 per thread.
__device__ inline void stage_k2(const bf16* kkbh, bf16* dst, int kb0, int kb1, int tid) {
    #pragma unroll
    for (int it = 0; it < 2; it++) {
        int o = (it * 256 + tid) * 16;            // byte offset within an 8KB block
        int row = o >> 7;
        int c16 = (o >> 4) & 7;
        int srcel = row * 64 + ((c16 ^ (row & 7)) << 3);   // element offset, swizzled source
        async_ld16(kkbh + (size_t)kb0 * (BLK * HD) + srcel, dst + (o >> 1));
        async_ld16(kkbh + (size_t)kb1 * (BLK * HD) + srcel, dst + 4096 + (o >> 1));
    }
}

// ---------------- prep: pad + cast X to bf16 ----------------
__global__ __launch_bounds__(256) void cast_pad_x(const float* __restrict__ X,
                                                  bf16* __restrict__ Xp) {
    int t = blockIdx.x * 256 + threadIdx.x;
    int c4 = t & 255;
    int row = t >> 8;
    int b = row >> 12;
    int s = row & 4095;
    float4 v = make_float4(0.f, 0.f, 0.f, 0.f);
    if (s < LQ) {
        v = reinterpret_cast<const float4*>(X + ((size_t)(b * LQ + s)) * HID)[c4];
    }
    union { bf16 h[4]; uint2 u; } o;
    o.h[0] = (bf16)v.x; o.h[1] = (bf16)v.y; o.h[2] = (bf16)v.z; o.h[3] = (bf16)v.w;
    *reinterpret_cast<uint2*>(Xp + (size_t)row * HID + c4 * 4) = o.u;
}

// ---------------- prep: transpose + cast weights ----------------
__global__ __launch_bounds__(256) void transpose_w(const float* __restrict__ Wq,
                                                   const float* __restrict__ Wk,
                                                   const float* __restrict__ Wv,
                                                   const float* __restrict__ Wo,
                                                   bf16* __restrict__ WqkvT,
                                                   bf16* __restrict__ WoT) {
    __shared__ float tile[64][65];
    int sel = blockIdx.z;
    const float* src = (sel == 0) ? Wq : (sel == 1) ? Wk : (sel == 2) ? Wv : Wo;
    bf16* dst = (sel < 3) ? (WqkvT + (size_t)sel * HID * HID) : WoT;
    int j0 = blockIdx.x * 64, k0 = blockIdx.y * 64;
    int tx = threadIdx.x, ty = threadIdx.y;   // (64,4)
    for (int i = 0; i < 16; i++) {
        int k = ty + i * 4;
        tile[k][tx] = src[(size_t)(k0 + k) * HID + j0 + tx];
    }
    __syncthreads();
    for (int i = 0; i < 16; i++) {
        int j = ty + i * 4;
        dst[(size_t)(j0 + j) * HID + k0 + tx] = (bf16)tile[tx][j];
    }
}

// ---------------- prep: transpose band mask ----------------
// band[b][l][q=64][k=192] -> bandT[b][l][k=192][q=64]
__global__ __launch_bounds__(256) void transpose_band(const float* __restrict__ band,
                                                      float* __restrict__ bandT) {
    __shared__ float tile[64][65];
    int kt = blockIdx.x;           // 0..2
    int lrow = blockIdx.y;         // 0..59
    int b = blockIdx.z;
    const float* src = band + ((size_t)(b * (NB - 4) + lrow) * BLK) * 192;
    float* dst = bandT + ((size_t)(b * (NB - 4) + lrow) * 192) * BLK;
    int tx = threadIdx.x, ty = threadIdx.y;   // (64,4)
    for (int i = 0; i < 16; i++) {
        int qq = i * 4 + ty;
        tile[qq][tx] = src[(size_t)qq * 192 + kt * 64 + tx];
    }
    __syncthreads();
    for (int i = 0; i < 16; i++) {
        int k = i * 4 + ty;
        dst[(size_t)(kt * 64 + k) * BLK + tx] = tile[tx][k];
    }
}

// ---------------- prep: mask violation flags (parallel) ----------------
__global__ __launch_bounds__(256) void mask_viol(const float* __restrict__ tom,
                                                 const float* __restrict__ blocked,
                                                 const float* __restrict__ band,
                                                 int* __restrict__ flags) {
    int which = blockIdx.y, b = blockIdx.z;
    const float* src;
    size_t n;
    if (which == 0)      { src = tom     + (size_t)b * SEQ;                  n = SEQ; }
    else if (which == 1) { src = blocked + (size_t)b * NB * BLK;             n = NB * BLK; }
    else                 { src = band    + (size_t)b * (NB - 4) * BLK * 192; n = (size_t)(NB - 4) * BLK * 192; }
    const float4* s4 = (const float4*)src;
    size_t n4 = n >> 2;
    int bad = 0;
    for (size_t i = blockIdx.x * 256 + threadIdx.x; i < n4; i += 240 * 256) {
        float4 v = s4[i];
        bad |= (v.x != 1.0f) | (v.y != 1.0f) | (v.z != 1.0f) | (v.w != 1.0f);
    }
    if (__any(bad) && (threadIdx.x & 63) == 0)
        atomicOr(&flags[which * BB + b], 1);
}

// ---------------- GEMM1: QKV projection ----------------
__global__ __launch_bounds__(256) void gemm_qkv(const bf16* __restrict__ Xp,
                                                const bf16* __restrict__ WT,
                                                const float* __restrict__ bq,
                                                const float* __restrict__ bk,
                                                const float* __restrict__ bv,
                                                bf16* __restrict__ qo,
                                                bf16* __restrict__ ko,
                                                bf16* __restrict__ vt) {
    __shared__ __align__(16) char smem[36864];   // staging 32KB; epi 4x9216B overlays
    bf16* As = (bf16*)smem;            // [128][64]
    bf16* Bs = As + 128 * 64;          // [128][64]
    int tid = threadIdx.x;
    int wave = tid >> 6, lane = tid & 63;
    int quad = lane >> 4, lm = lane & 15;
    int id = blockIdx.x;
    int xcd = id & 7, slot = id >> 3;
    int tile_m = (xcd * 8 + (slot & 7)) * 128;   // 64 tile_m rows across 8 XCDs
    int tile_n = (slot >> 3) * 128;              // 24 tile_n cols
    int wm = (wave & 1) * 64, wn = (wave >> 1) * 64;

    floatx4 acc[4][4] = {};

    for (int k0 = 0; k0 < HID; k0 += 64) {
        __syncthreads();
        for (int it = 0; it < 4; it++) {
            int c = it * 256 + tid;           // LDS offset = c*16B (lane-contig)
            int row = c >> 3, col = (c & 7) * 8;
            async_ld16(Xp + (size_t)(tile_m + row) * HID + k0 + col, &As[c * 8]);
            async_ld16(WT + (size_t)(tile_n + row) * HID + k0 + col, &Bs[c * 8]);
        }
        __syncthreads();
        for (int ks = 0; ks < 64; ks += 32) {
            bf16x8 a[4], b[4];
            for (int i = 0; i < 4; i++)
                a[i] = *reinterpret_cast<const bf16x8*>(&As[(wm + i * 16 + lm) * 64 + ks + quad * 8]);
            for (int j = 0; j < 4; j++)
                b[j] = *reinterpret_cast<const bf16x8*>(&Bs[(wn + j * 16 + lm) * 64 + ks + quad * 8]);
            for (int i = 0; i < 4; i++)
                for (int j = 0; j < 4; j++)
                    acc[i][j] = mfma16(a[i], b[j], acc[i][j]);
        }
    }

    int which = tile_n >> 10;                 // 0=q,1=k,2=v (wave-uniform)
    int hc_base = (tile_n + wn) & 1023;       // multiple of 64
    int h = hc_base >> 6;
    const float* bias = (which == 0) ? bq : (which == 1) ? bk : bv;
    __syncthreads();                          // retire all staging reads before overlay
    bf16* ep = (bf16*)smem + wave * (64 * 72);

    if (which < 2) {
        #pragma unroll
        for (int i = 0; i < 4; i++)
            #pragma unroll
            for (int j = 0; j < 4; j++) {
                float bsv = bias[hc_base + j * 16 + lm];
                #pragma unroll
                for (int r = 0; r < 4; r++) {
                    float val = acc[i][j][r] + bsv;
                    if (which == 0) val *= 0.125f;
                    ep[(i * 16 + quad * 4 + r) * 72 + j * 16 + lm] = (bf16)val;
                }
            }
        __builtin_amdgcn_wave_barrier();
        int s_glob = tile_m + wm + lane;
        int b_ = s_glob >> 12, s = s_glob & 4095;
        bf16* dstb = ((which == 0) ? qo : ko) + ((size_t)((b_ * NH + h) * SEQ + s)) * HD;
        #pragma unroll
        for (int c = 0; c < 8; c++)
            *reinterpret_cast<uint4*>(dstb + c * 8) =
                *reinterpret_cast<const uint4*>(ep + lane * 72 + c * 8);
    } else {
        #pragma unroll
        for (int i = 0; i < 4; i++)
            #pragma unroll
            for (int j = 0; j < 4; j++) {
                float bsv = bias[hc_base + j * 16 + lm];
                #pragma unroll
                for (int r = 0; r < 4; r++) {
                    float val = acc[i][j][r] + bsv;
                    ep[(j * 16 + lm) * 72 + i * 16 + quad * 4 + r] = (bf16)val;
                }
            }
        __builtin_amdgcn_wave_barrier();
        int s_base = tile_m + wm;
        int b_ = s_base >> 12, s0 = s_base & 4095;
        bf16* dstb = vt + ((size_t)((b_ * NH + h) * HD + lane)) * SEQ + s0;
        #pragma unroll
        for (int c = 0; c < 8; c++)
            *reinterpret_cast<uint4*>(dstb + c * 8) =
                *reinterpret_cast<const uint4*>(ep + lane * 72 + c * 8);
    }
}

// ---------------- attention ----------------
// Round-9 structure (106.6us: in-register P transpose, 32KB LDS) +
// s_setprio(1) around the QK and PV MFMA clusters (T5, +4-7% attn per m191:
// free-running waves at different phases -> scheduler favors MFMA-entering
// waves over load-issuing ones).
__global__ __launch_bounds__(256, 2) void attn_kernel(const bf16* __restrict__ q,
                                                      const bf16* __restrict__ kk,
                                                      const bf16* __restrict__ vt,
                                                      const float* __restrict__ bandT,
                                                      const float* __restrict__ fromm,
                                                      const float* __restrict__ tom,
                                                      const float* __restrict__ blocked,
                                                      const int* __restrict__ rand_attn,
                                                      const int* __restrict__ flags,
                                                      bf16* __restrict__ attn) {
    // [0,32768): K staging, 2 buffers x (2 blocks x 4096 elems).
    // Fullmode: combine overlay (ctxL 16KB + mL/lL 512B) -- staging unused there.
    __shared__ __align__(16) char smem[32768];
    bf16* sK = (bf16*)smem;

    int tid = threadIdx.x, wave = tid >> 6, lane = tid & 63;
    int quad = lane >> 4, lm = lane & 15;
    int sw = lm & 7;                        // K-swizzle row key ((f*16+lm)&7 == lm&7)
    int bh = blockIdx.x;
    int b = bh >> 4, h = bh & 15;
    size_t bh_base = (size_t)bh * SEQ * HD;
    int x = blockIdx.y;
    bool fullmode = (x < 8);
    int l, sub;
    if (fullmode) { l = (x >> 2) ? (NB - 1) : 0; sub = x & 3; }
    else          { l = x - 7;                   sub = wave;  }

    bool do_to = flags[b] != 0;          // to_mask has non-ones
    bool do_bl = flags[BB + b] != 0;     // blocked has non-ones
    bool do_bd = flags[2 * BB + b] != 0; // band has non-ones

    // key-block list (middle mode), packed: kbp = 8 x 6-bit block ids (byte lanes),
    // typ_p = 8 x 4-bit types. type: 0=to_mask, 1..3=band(t), 4=rand, 5=pad.
    unsigned long long kbp = 0ull;
    unsigned int typ_p = 0u;
    if (!fullmode) {
        int base;
        if (l == 1) {
            kbp = (1ull << 8) | (2ull << 16) | ((unsigned long long)(NB - 1) << 24);
            base = 4;
        } else if (l == NB - 2) {
            kbp = ((unsigned long long)(NB - 3) << 8) | ((unsigned long long)(NB - 2) << 16) |
                  ((unsigned long long)(NB - 1) << 24);
            base = 4;
        } else {
            kbp = ((unsigned long long)(l - 1) << 8) | ((unsigned long long)l << 16) |
                  ((unsigned long long)(l + 1) << 24) | ((unsigned long long)(NB - 1) << 32);
            typ_p = (1u << 4) | (2u << 8) | (3u << 12);
            base = 5;
        }
        const int* ra = rand_attn + ((size_t)(b * NH + h) * (NB - 2) + (l - 1)) * NR;
        #pragma unroll
        for (int r = 0; r < NR; r++) {
            int rv = __builtin_amdgcn_readfirstlane(ra[r]);
            kbp   |= (unsigned long long)(rv & 63) << ((base + r) * 8);
            typ_p |= 4u << ((base + r) * 4);
        }
        for (int i = base + NR; i < 8; i++) typ_p |= 5u << (i * 4);   // pads (kb=0, masked off)
    }

    // Q fragments + per-lane query mask (issued before staging so the c0 wait
    // retires them together with the prologue stage; latencies overlap).
    bf16x8 aq0 = *reinterpret_cast<const bf16x8*>(
        q + bh_base + (size_t)(l * BLK + sub * 16 + lm) * HD + quad * 8);
    bf16x8 aq1 = *reinterpret_cast<const bf16x8*>(
        q + bh_base + (size_t)(l * BLK + sub * 16 + lm) * HD + 32 + quad * 8);
    float mq = blocked[((size_t)b * NB + l) * BLK + sub * 16 + lm];

    if (!fullmode) {
        MEMFENCE;
        int a0 = (int)((kbp >> 0) & 63),  a1 = (int)((kbp >> 8) & 63);
        int b0 = (int)((kbp >> 16) & 63), b1 = (int)((kbp >> 24) & 63);
        stage_k2(kk + bh_base, sK + 0,    a0, a1, tid);
        stage_k2(kk + bh_base, sK + 8192, b0, b1, tid);
        MEMFENCE;
    }

    floatx4 ctx[4] = {};        // O^T: d=dj*16+quad*4+r, query=lm
    float mrun = -1e30f, lrun = 0.f;   // lrun: PER-LANE partial (reduced at end)

    int sbase = ((quad & 1) << 5) + lm;   // source lane pair base for P shuffle
    int fhi = quad >> 1;                  // f-register select for P shuffle

    int nch = fullmode ? 8 : 4;
    for (int ch = 0; ch < nch; ch++) {
        int i0 = ch * 2, i1 = i0 + 1;
        int kb0, kb1, ty0, ty1;
        if (fullmode) {
            kb0 = __builtin_amdgcn_readfirstlane(wave * 16 + i0);
            kb1 = kb0 + 1;
            ty0 = 0; ty1 = 0;
        } else {
            kb0 = __builtin_amdgcn_readfirstlane((int)((kbp >> (i0 * 8)) & 63));
            kb1 = __builtin_amdgcn_readfirstlane((int)((kbp >> (i1 * 8)) & 63));
            ty0 = (int)((typ_p >> (i0 * 4)) & 15);
            ty1 = (int)((typ_p >> (i1 * 4)) & 15);
        }

        // ---- vf0 issue FIRST (addresses independent of K) ----
        const bf16* v0p = vt + bh_base + (size_t)kb0 * BLK;
        bf16x8 vf0[4][2];
        #pragma unroll
        for (int dj = 0; dj < 4; dj++) {
            vf0[dj][0] = *reinterpret_cast<const bf16x8*>(v0p + (size_t)(dj * 16 + lm) * SEQ + quad * 8);
            vf0[dj][1] = *reinterpret_cast<const bf16x8*>(v0p + (size_t)(dj * 16 + lm) * SEQ + 32 + quad * 8);
        }
        MEMFENCE;

        // ---- scores: S^T = K * Q^T; sc[u][f][r] = S^T[key=f*16+quad*4+r][q=lm] ----
        floatx4 sc[2][4];
        if (!fullmode) {
            // own stage (issued last chunk / prologue) retired; vf0 kept in flight
            if (ch < 3) asm volatile("s_waitcnt vmcnt(8)" ::: "memory");
            else        asm volatile("s_waitcnt vmcnt(16)" ::: "memory");  // stage(8) only
            __builtin_amdgcn_s_barrier();
            const bf16* kbuf = sK + (ch & 1) * 8192;
            __builtin_amdgcn_s_setprio(1);
            #pragma unroll
            for (int u = 0; u < 2; u++) {
                bf16x8 ka[4], kb_[4];
                #pragma unroll
                for (int f = 0; f < 4; f++) {
                    int rowb = (f * 16 + lm) * 64;
                    ka[f]  = *reinterpret_cast<const bf16x8*>(
                        kbuf + u * 4096 + rowb + ((quad ^ sw) << 3));
                    kb_[f] = *reinterpret_cast<const bf16x8*>(
                        kbuf + u * 4096 + rowb + (((quad | 4) ^ sw) << 3));
                }
                #pragma unroll
                for (int f = 0; f < 4; f++) {
                    floatx4 z = {0.f, 0.f, 0.f, 0.f};
                    z = mfma16(ka[f], aq0, z);
                    z = mfma16(kb_[f], aq1, z);
                    sc[u][f] = z;
                }
            }
            __builtin_amdgcn_s_setprio(0);
        } else {
            const bf16* k0p = kk + bh_base + (size_t)kb0 * (BLK * HD);
            const bf16* k1p = kk + bh_base + (size_t)kb1 * (BLK * HD);
            bf16x8 kfa[2][4], kfb[2][4];
            #pragma unroll
            for (int f = 0; f < 4; f++) {
                kfa[0][f] = *reinterpret_cast<const bf16x8*>(k0p + (f * 16 + lm) * HD + quad * 8);
                kfb[0][f] = *reinterpret_cast<const bf16x8*>(k0p + (f * 16 + lm) * HD + 32 + quad * 8);
                kfa[1][f] = *reinterpret_cast<const bf16x8*>(k1p + (f * 16 + lm) * HD + quad * 8);
                kfb[1][f] = *reinterpret_cast<const bf16x8*>(k1p + (f * 16 + lm) * HD + 32 + quad * 8);
            }
            __builtin_amdgcn_s_setprio(1);
            #pragma unroll
            for (int u = 0; u < 2; u++)
                #pragma unroll
                for (int f = 0; f < 4; f++) {
                    floatx4 z = {0.f, 0.f, 0.f, 0.f};
                    z = mfma16(kfa[u][f], aq0, z);
                    z = mfma16(kfb[u][f], aq1, z);
                    sc[u][f] = z;
                }
            __builtin_amdgcn_s_setprio(0);
        }

        // ---- vf1 issue (after QK so K frags are dead; ~600cy before PV1 use) ----
        const bf16* v1p = vt + bh_base + (size_t)kb1 * BLK;
        bf16x8 vf1[4][2];
        #pragma unroll
        for (int dj = 0; dj < 4; dj++) {
            vf1[dj][0] = *reinterpret_cast<const bf16x8*>(v1p + (size_t)(dj * 16 + lm) * SEQ + quad * 8);
            vf1[dj][1] = *reinterpret_cast<const bf16x8*>(v1p + (size_t)(dj * 16 + lm) * SEQ + 32 + quad * 8);
        }
        MEMFENCE;

        // ---- masks (key = f*16+quad*4+r, query = lm); skipped when mask all-ones ----
        {
            int kbs[2] = {kb0, kb1};
            int tys[2] = {ty0, ty1};
            #pragma unroll
            for (int u = 0; u < 2; u++) {
                int kb = kbs[u], typ = tys[u];
                if (typ == 0) {
                    if (do_to) {
                        #pragma unroll
                        for (int f = 0; f < 4; f++) {
                            float4 t4 = *reinterpret_cast<const float4*>(
                                tom + (size_t)b * SEQ + kb * BLK + f * 16 + quad * 4);
                            sc[u][f][0] += (1.f - t4.x) * PENV;
                            sc[u][f][1] += (1.f - t4.y) * PENV;
                            sc[u][f][2] += (1.f - t4.z) * PENV;
                            sc[u][f][3] += (1.f - t4.w) * PENV;
                        }
                    }
                } else if (typ == 4) {
                    if (do_bl) {
                        #pragma unroll
                        for (int f = 0; f < 4; f++) {
                            float4 t4 = *reinterpret_cast<const float4*>(
                                blocked + ((size_t)b * NB + kb) * BLK + f * 16 + quad * 4);
                            sc[u][f][0] += (1.f - mq * t4.x) * PENV;
                            sc[u][f][1] += (1.f - mq * t4.y) * PENV;
                            sc[u][f][2] += (1.f - mq * t4.z) * PENV;
                            sc[u][f][3] += (1.f - mq * t4.w) * PENV;
                        }
                    }
                } else if (typ != 5) {
                    if (do_bd) {
                        int t = typ - 1;
                        const float* bp = bandT + ((size_t)(b * (NB - 4) + (l - 2)) * 192 + t * 64) * BLK;
                        #pragma unroll
                        for (int f = 0; f < 4; f++)
                            #pragma unroll
                            for (int r = 0; r < 4; r++) {
                                float bm = bp[(size_t)(f * 16 + quad * 4 + r) * BLK + sub * 16 + lm];
                                sc[u][f][r] += (1.f - bm) * PENV;
                            }
                    }
                } else {
                    #pragma unroll
                    for (int f = 0; f < 4; f++)
                        #pragma unroll
                        for (int r = 0; r < 4; r++) sc[u][f][r] += PENV;
                }
            }
        }

        // ---- softmax: chunk max via 3 PARALLEL shuffles (one DS latency) ----
        float mx = -1e30f;
        #pragma unroll
        for (int u = 0; u < 2; u++)
            #pragma unroll
            for (int f = 0; f < 4; f++)
                #pragma unroll
                for (int r = 0; r < 4; r++) mx = fmaxf(mx, sc[u][f][r]);
        float a16 = __shfl_xor(mx, 16, 64);
        float a32 = __shfl_xor(mx, 32, 64);
        float a48 = __shfl_xor(mx, 48, 64);
        mx = fmaxf(fmaxf(mx, a16), fmaxf(a32, a48));
        float mnew = fmaxf(mrun, mx);
        float scale = __expf(mrun - mnew);
        #pragma unroll
        for (int dj = 0; dj < 4; dj++) ctx[dj] *= scale;
        mrun = mnew;

        // ---- exp -> packed bf16 pairs (in register); per-lane partial row-sum ----
        float rs = 0.f;
        uint2 pk[2][4];
        #pragma unroll
        for (int u = 0; u < 2; u++)
            #pragma unroll
            for (int f = 0; f < 4; f++) {
                float p0 = __expf(sc[u][f][0] - mnew);
                float p1 = __expf(sc[u][f][1] - mnew);
                float p2 = __expf(sc[u][f][2] - mnew);
                float p3 = __expf(sc[u][f][3] - mnew);
                rs += (p0 + p1) + (p2 + p3);
                union { bf16 hh[4]; uint2 u2; } pu;
                pu.hh[0] = (bf16)p0; pu.hh[1] = (bf16)p1;
                pu.hh[2] = (bf16)p2; pu.hh[3] = (bf16)p3;
                pk[u][f] = pu.u2;
            }
        lrun = lrun * scale + rs;          // per-lane partial; reduced once at end

        // ---- in-register P transpose: sc layout -> PV B-operand layout ----
        bf16x8 pb[2][2];
        #pragma unroll
        for (int u = 0; u < 2; u++) {
            unsigned g0x[4], g0y[4], g1x[4], g1y[4];
            #pragma unroll
            for (int f = 0; f < 4; f++) {
                g0x[f] = (unsigned)__shfl((int)pk[u][f].x, sbase, 64);
                g0y[f] = (unsigned)__shfl((int)pk[u][f].y, sbase, 64);
                g1x[f] = (unsigned)__shfl((int)pk[u][f].x, sbase + 16, 64);
                g1y[f] = (unsigned)__shfl((int)pk[u][f].y, sbase + 16, 64);
            }
            union { unsigned v[4]; bf16x8 hv; } lo, hi;
            lo.v[0] = fhi ? g0x[1] : g0x[0];
            lo.v[1] = fhi ? g0y[1] : g0y[0];
            lo.v[2] = fhi ? g1x[1] : g1x[0];
            lo.v[3] = fhi ? g1y[1] : g1y[0];
            hi.v[0] = fhi ? g0x[3] : g0x[2];
            hi.v[1] = fhi ? g0y[3] : g0y[2];
            hi.v[2] = fhi ? g1x[3] : g1x[2];
            hi.v[3] = fhi ? g1y[3] : g1y[2];
            pb[u][0] = lo.hv;
            pb[u][1] = hi.hv;
        }

        // ---- stage chunk ch+1's K (ISSUED LAST so PV waits never drain it) ----
        if (!fullmode && ch >= 1 && ch + 1 < 4) {
            int na = __builtin_amdgcn_readfirstlane((int)((kbp >> ((ch + 1) * 16)) & 63));
            int nb = __builtin_amdgcn_readfirstlane((int)((kbp >> ((ch + 1) * 16 + 8)) & 63));
            stage_k2(kk + bh_base, sK + ((ch + 1) & 1) * 8192, na, nb, tid);
            MEMFENCE;
        }

        // ---- PV blocks (auto-wait vmcnt keeps vf1 + staged K in flight) ----
        __builtin_amdgcn_s_setprio(1);
        #pragma unroll
        for (int dj = 0; dj < 4; dj++) {
            ctx[dj] = mfma16(vf0[dj][0], pb[0][0], ctx[dj]);
            ctx[dj] = mfma16(vf0[dj][1], pb[0][1], ctx[dj]);
        }
        #pragma unroll
        for (int dj = 0; dj < 4; dj++) {
            ctx[dj] = mfma16(vf1[dj][0], pb[1][0], ctx[dj]);
            ctx[dj] = mfma16(vf1[dj][1], pb[1][1], ctx[dj]);
        }
        __builtin_amdgcn_s_setprio(0);
    }

    // ---- deferred l-sum reduce: 3 parallel shuffles, once per kernel ----
    {
        float b16 = __shfl_xor(lrun, 16, 64);
        float b32 = __shfl_xor(lrun, 32, 64);
        float b48 = __shfl_xor(lrun, 48, 64);
        lrun = (lrun + b16) + (b32 + b48);
    }

    if (!fullmode) {
        // per-lane finalize: query = lm
        int sq = l * BLK + sub * 16 + lm;
        float w = (1.f / lrun) * fromm[(size_t)b * SEQ + sq];
        bf16* dst = attn + ((size_t)(b * SEQ + sq)) * HID + h * HD;
        #pragma unroll
        for (int dj = 0; dj < 4; dj++) {
            union { bf16 hh[4]; uint2 u2; } o;
            #pragma unroll
            for (int r = 0; r < 4; r++) o.hh[r] = (bf16)(ctx[dj][r] * w);
            *reinterpret_cast<uint2*>(dst + dj * 16 + quad * 4) = o.u2;
        }
    } else {
        // cross-wave combine (4 partials over the same 16 queries)
        float* ctxL = (float*)smem;                    // [wave][d=64][q=16] (staging region, free)
        float* mL   = (float*)(smem + 16384);          // [wave][16]
        float* lL   = (float*)(smem + 16640);          // [wave][16]
        __syncthreads();
        #pragma unroll
        for (int dj = 0; dj < 4; dj++)
            #pragma unroll
            for (int r = 0; r < 4; r++)
                ctxL[wave * 1024 + (dj * 16 + quad * 4 + r) * 16 + lm] = ctx[dj][r];
        if (quad == 0) { mL[wave * 16 + lm] = mrun; lL[wave * 16 + lm] = lrun; }
        __syncthreads();
        int qq = tid & 15, dbase = (tid >> 4) * 4;
        float M = -1e30f;
        for (int w = 0; w < 4; w++) M = fmaxf(M, mL[w * 16 + qq]);
        float e[4], Lt = 0.f;
        for (int w = 0; w < 4; w++) { e[w] = __expf(mL[w * 16 + qq] - M); Lt += lL[w * 16 + qq] * e[w]; }
        int sq = l * BLK + sub * 16 + qq;
        float wgt = (1.f / Lt) * fromm[(size_t)b * SEQ + sq];
        union { bf16 hh[4]; uint2 u2; } o;
        #pragma unroll
        for (int dd = 0; dd < 4; dd++) {
            float acc = 0.f;
            for (int w = 0; w < 4; w++) acc += ctxL[w * 1024 + (dbase + dd) * 16 + qq] * e[w];
            o.hh[dd] = (bf16)(acc * wgt);
        }
        *reinterpret_cast<uint2*>(attn + ((size_t)(b * SEQ + sq)) * HID + h * HD + dbase) = o.u2;
    }
}

// ---------------- GEMM2: output projection ----------------
// 2-phase double-buffered K-pipeline (T3 minimum pattern): stage tile t+1
// BEFORE computing tile t; single __syncthreads per tile (emits vmcnt(0)+
// lgkmcnt(0)+s_barrier) -- race-free: every wave's ds_reads of buf[t] retire
// before the barrier that precedes buf[t]'s re-staging. Stage latency hides
// under ds_read+MFMA instead of being serially exposed (grid=512 -> only
// 2 blocks/CU, so TLP can't hide it; dbuf LDS 64KB is free at this residency).
__global__ __launch_bounds__(256) void gemm_out(const bf16* __restrict__ A,
                                                const bf16* __restrict__ WoT,
                                                const float* __restrict__ bo,
                                                float* __restrict__ out) {
    __shared__ __align__(16) char smem[65536];   // 2 x (As 16KB + Bs 16KB)
    int tid = threadIdx.x;
    int wave = tid >> 6, lane = tid & 63;
    int quad = lane >> 4, lm = lane & 15;
    int id = blockIdx.x;
    int xcd = id & 7, slot = id >> 3;
    int tile_m = (xcd * 8 + (slot & 7)) * 128;
    int tile_n = (slot >> 3) * 128;
    int wm = (wave & 1) * 64, wn = (wave >> 1) * 64;

    floatx4 acc[4][4] = {};

    // prologue: stage tile 0 into buffer 0
    {
        bf16* base = (bf16*)smem;
        #pragma unroll
        for (int it = 0; it < 4; it++) {
            int c = it * 256 + tid;
            int row = c >> 3, col = (c & 7) * 8;
            async_ld16(A + (size_t)(tile_m + row) * HID + col, &base[c * 8]);
            async_ld16(WoT + (size_t)(tile_n + row) * HID + col, &base[8192 + c * 8]);
        }
    }
    __syncthreads();   // buf0 landed

    for (int t = 0; t < 16; t++) {
        // stage tile t+1 into the other buffer (in flight during compute)
        if (t < 15) {
            bf16* base = (bf16*)smem + ((t + 1) & 1) * 16384;
            int k0 = (t + 1) * 64;
            #pragma unroll
            for (int it = 0; it < 4; it++) {
                int c = it * 256 + tid;
                int row = c >> 3, col = (c & 7) * 8;
                async_ld16(A + (size_t)(tile_m + row) * HID + k0 + col, &base[c * 8]);
                async_ld16(WoT + (size_t)(tile_n + row) * HID + k0 + col, &base[8192 + c * 8]);
            }
        }
        const bf16* As = (const bf16*)smem + (t & 1) * 16384;
        const bf16* Bs = As + 8192;
        #pragma unroll
        for (int ks = 0; ks < 64; ks += 32) {
            bf16x8 a[4], b[4];
            for (int i = 0; i < 4; i++)
                a[i] = *reinterpret_cast<const bf16x8*>(&As[(wm + i * 16 + lm) * 64 + ks + quad * 8]);
            for (int j = 0; j < 4; j++)
                b[j] = *reinterpret_cast<const bf16x8*>(&Bs[(wn + j * 16 + lm) * 64 + ks + quad * 8]);
            for (int i = 0; i < 4; i++)
                for (int j = 0; j < 4; j++)
                    acc[i][j] = mfma16(a[i], b[j], acc[i][j]);
        }
        __syncthreads();   // stage t+1 landed; all waves done reading buf[t]
    }

    for (int i = 0; i < 4; i++) {
        for (int j = 0; j < 4; j++) {
            int nn = tile_n + wn + j * 16 + lm;
            float bsv = bo[nn];
            for (int r = 0; r < 4; r++) {
                int mm = tile_m + wm + i * 16 + quad * 4 + r;
                int b_ = mm >> 12, s = mm & 4095;
                if (s < LQ)
                    out[((size_t)(b_ * LQ + s)) * HID + nn] = acc[i][j][r] + bsv;
            }
        }
    }
}

// ---------------- launcher ----------------
extern "C" void kernel_launch(void* const* d_in, const int* in_sizes, int n_in,
                              void* d_out, int out_size, void* d_ws, size_t ws_size,
                              hipStream_t stream) {
    const float* X       = (const float*)d_in[0];
    const float* Wq      = (const float*)d_in[1];
    const float* bq      = (const float*)d_in[2];
    const float* Wk      = (const float*)d_in[3];
    const float* bk      = (const float*)d_in[4];
    const float* Wv      = (const float*)d_in[5];
    const float* bv      = (const float*)d_in[6];
    const float* Wo      = (const float*)d_in[7];
    const float* bo      = (const float*)d_in[8];
    const float* band    = (const float*)d_in[9];
    const float* fromm   = (const float*)d_in[10];
    const float* tom     = (const float*)d_in[11];
    const float* blocked = (const float*)d_in[12];
    const int*   randa   = (const int*)d_in[13];
    float* out = (float*)d_out;

    char* ws = (char*)d_ws;
    bf16* Xp    = (bf16*)(ws + 0);              // 16,777,216 B (reused as attn)
    bf16* WqkvT = (bf16*)(ws + 16777216);       //  6,291,456 B (reused as bandT+flags after gemm_qkv)
    bf16* WoT   = (bf16*)(ws + 23068672);       //  2,097,152 B
    bf16* qb    = (bf16*)(ws + 25165824);       // 16,777,216 B
    bf16* kb    = (bf16*)(ws + 41943040);       // 16,777,216 B
    bf16* vtb   = (bf16*)(ws + 58720256);       // 16,777,216 B (d-major V)
    bf16* attnb = Xp;                           // Xp dead after gemm_qkv
    float* bandT = (float*)WqkvT;               // 5,898,240 B, alive only during attn
    int* flagsp = (int*)(ws + 16777216 + 5898240);  // 24 B, inside dead WqkvT tail

    cast_pad_x<<<dim3(8192), dim3(256), 0, stream>>>(X, Xp);
    transpose_w<<<dim3(16, 16, 4), dim3(64, 4), 0, stream>>>(Wq, Wk, Wv, Wo, WqkvT, WoT);
    gemm_qkv<<<dim3(1536), dim3(256), 0, stream>>>(Xp, WqkvT, bq, bk, bv, qb, kb, vtb);
    transpose_band<<<dim3(3, NB - 4, BB), dim3(64, 4), 0, stream>>>(band, bandT);
    hipMemsetAsync(flagsp, 0, 3 * BB * sizeof(int), stream);
    mask_viol<<<dim3(240, 3, BB), dim3(256), 0, stream>>>(tom, blocked, band, flagsp);
    attn_kernel<<<dim3(BB * NH, 70), dim3(256), 0, stream>>>(qb, kb, vtb, bandT, fromm, tom,
                                                             blocked, randa, flagsp, attnb);
    gemm_out<<<dim3(512), dim3(256), 0, stream>>>(attnb, WoT, bo, out);
}

// Round 11
// 328.784 us; speedup vs baseline: 1.0394x; 1.0161x over previous
//
#include <hip/hip_runtime.h>

// ---------------- constants ----------------
#define BB 2
#define SEQ 4096
#define LQ 4064
#define HID 1024
#define NH 16
#define HD 64
#define NB 64      // number of 64-wide blocks in sequence
#define BLK 64
#define NR 3
#define PENV -10000.0f

typedef __bf16 bf16;
typedef __bf16 bf16x8 __attribute__((ext_vector_type(8)));
typedef float floatx4 __attribute__((ext_vector_type(4)));

#define MEMFENCE asm volatile("" ::: "memory")

__device__ inline floatx4 mfma16(bf16x8 a, bf16x8 b, floatx4 c) {
    return __builtin_amdgcn_mfma_f32_16x16x32_bf16(a, b, c, 0, 0, 0);
}

// async global->LDS, 16B per lane (global_load_lds_dwordx4)
__device__ inline void async_ld16(const bf16* g, bf16* l) {
    __builtin_amdgcn_global_load_lds(
        (const __attribute__((address_space(1))) unsigned int*)g,
        (__attribute__((address_space(3))) unsigned int*)l, 16, 0, 0);
}

// stage 2 K blocks (8KB each) into LDS dst (linear), source pre-swizzled so that
// LDS[row][c16] = G[row][c16 ^ (row&7)]  (c16 = 16B column within 128B row).
// 4 async_ld16 per thread.
__device__ inline void stage_k2(const bf16* kkbh, bf16* dst, int kb0, int kb1, int tid) {
    #pragma unroll
    for (int it = 0; it < 2; it++) {
        int o = (it * 256 + tid) * 16;            // byte offset within an 8KB block
        int row = o >> 7;
        int c16 = (o >> 4) & 7;
        int srcel = row * 64 + ((c16 ^ (row & 7)) << 3);   // element offset, swizzled source
        async_ld16(kkbh + (size_t)kb0 * (BLK * HD) + srcel, dst + (o >> 1));
        async_ld16(kkbh + (size_t)kb1 * (BLK * HD) + srcel, dst + 4096 + (o >> 1));
    }
}

// ---------------- prep: pad + cast X to bf16 ----------------
__global__ __launch_bounds__(256) void cast_pad_x(const float* __restrict__ X,
                                                  bf16* __restrict__ Xp) {
    int t = blockIdx.x * 256 + threadIdx.x;
    int c4 = t & 255;
    int row = t >> 8;
    int b = row >> 12;
    int s = row & 4095;
    float4 v = make_float4(0.f, 0.f, 0.f, 0.f);
    if (s < LQ) {
        v = reinterpret_cast<const float4*>(X + ((size_t)(b * LQ + s)) * HID)[c4];
    }
    union { bf16 h[4]; uint2 u; } o;
    o.h[0] = (bf16)v.x; o.h[1] = (bf16)v.y; o.h[2] = (bf16)v.z; o.h[3] = (bf16)v.w;
    *reinterpret_cast<uint2*>(Xp + (size_t)row * HID + c4 * 4) = o.u;
}

// ---------------- prep: transpose + cast weights ----------------
__global__ __launch_bounds__(256) void transpose_w(const float* __restrict__ Wq,
                                                   const float* __restrict__ Wk,
                                                   const float* __restrict__ Wv,
                                                   const float* __restrict__ Wo,
                                                   bf16* __restrict__ WqkvT,
                                                   bf16* __restrict__ WoT) {
    __shared__ float tile[64][65];
    int sel = blockIdx.z;
    const float* src = (sel == 0) ? Wq : (sel == 1) ? Wk : (sel == 2) ? Wv : Wo;
    bf16* dst = (sel < 3) ? (WqkvT + (size_t)sel * HID * HID) : WoT;
    int j0 = blockIdx.x * 64, k0 = blockIdx.y * 64;
    int tx = threadIdx.x, ty = threadIdx.y;   // (64,4)
    for (int i = 0; i < 16; i++) {
        int k = ty + i * 4;
        tile[k][tx] = src[(size_t)(k0 + k) * HID + j0 + tx];
    }
    __syncthreads();
    for (int i = 0; i < 16; i++) {
        int j = ty + i * 4;
        dst[(size_t)(j0 + j) * HID + k0 + tx] = (bf16)tile[tx][j];
    }
}

// ---------------- prep: transpose band mask ----------------
// band[b][l][q=64][k=192] -> bandT[b][l][k=192][q=64]
__global__ __launch_bounds__(256) void transpose_band(const float* __restrict__ band,
                                                      float* __restrict__ bandT) {
    __shared__ float tile[64][65];
    int kt = blockIdx.x;           // 0..2
    int lrow = blockIdx.y;         // 0..59
    int b = blockIdx.z;
    const float* src = band + ((size_t)(b * (NB - 4) + lrow) * BLK) * 192;
    float* dst = bandT + ((size_t)(b * (NB - 4) + lrow) * 192) * BLK;
    int tx = threadIdx.x, ty = threadIdx.y;   // (64,4)
    for (int i = 0; i < 16; i++) {
        int qq = i * 4 + ty;
        tile[qq][tx] = src[(size_t)qq * 192 + kt * 64 + tx];
    }
    __syncthreads();
    for (int i = 0; i < 16; i++) {
        int k = i * 4 + ty;
        dst[(size_t)(kt * 64 + k) * BLK + tx] = tile[tx][k];
    }
}

// ---------------- prep: mask violation flags (parallel) ----------------
__global__ __launch_bounds__(256) void mask_viol(const float* __restrict__ tom,
                                                 const float* __restrict__ blocked,
                                                 const float* __restrict__ band,
                                                 int* __restrict__ flags) {
    int which = blockIdx.y, b = blockIdx.z;
    const float* src;
    size_t n;
    if (which == 0)      { src = tom     + (size_t)b * SEQ;                  n = SEQ; }
    else if (which == 1) { src = blocked + (size_t)b * NB * BLK;             n = NB * BLK; }
    else                 { src = band    + (size_t)b * (NB - 4) * BLK * 192; n = (size_t)(NB - 4) * BLK * 192; }
    const float4* s4 = (const float4*)src;
    size_t n4 = n >> 2;
    int bad = 0;
    for (size_t i = blockIdx.x * 256 + threadIdx.x; i < n4; i += 240 * 256) {
        float4 v = s4[i];
        bad |= (v.x != 1.0f) | (v.y != 1.0f) | (v.z != 1.0f) | (v.w != 1.0f);
    }
    if (__any(bad) && (threadIdx.x & 63) == 0)
        atomicOr(&flags[which * BB + b], 1);
}

// ---------------- GEMM1: QKV projection ----------------
// 2-phase double-buffered K-pipeline (same pattern as gemm_out, which measured
// -13us): stage tile t+1 BEFORE computing tile t; one __syncthreads per tile.
// LDS 64KB staging (2 x 32KB); epilogue overlay (36864B) fits under it.
__global__ __launch_bounds__(256) void gemm_qkv(const bf16* __restrict__ Xp,
                                                const bf16* __restrict__ WT,
                                                const float* __restrict__ bq,
                                                const float* __restrict__ bk,
                                                const float* __restrict__ bv,
                                                bf16* __restrict__ qo,
                                                bf16* __restrict__ ko,
                                                bf16* __restrict__ vt) {
    __shared__ __align__(16) char smem[65536];   // 2 x (As 16KB + Bs 16KB); epi overlays
    int tid = threadIdx.x;
    int wave = tid >> 6, lane = tid & 63;
    int quad = lane >> 4, lm = lane & 15;
    int id = blockIdx.x;
    int xcd = id & 7, slot = id >> 3;
    int tile_m = (xcd * 8 + (slot & 7)) * 128;   // 64 tile_m rows across 8 XCDs
    int tile_n = (slot >> 3) * 128;              // 24 tile_n cols
    int wm = (wave & 1) * 64, wn = (wave >> 1) * 64;

    floatx4 acc[4][4] = {};

    // prologue: stage tile 0 into buffer 0
    {
        bf16* base = (bf16*)smem;
        #pragma unroll
        for (int it = 0; it < 4; it++) {
            int c = it * 256 + tid;           // LDS offset = c*16B (lane-contig)
            int row = c >> 3, col = (c & 7) * 8;
            async_ld16(Xp + (size_t)(tile_m + row) * HID + col, &base[c * 8]);
            async_ld16(WT + (size_t)(tile_n + row) * HID + col, &base[8192 + c * 8]);
        }
    }
    __syncthreads();   // buf0 landed

    for (int t = 0; t < 16; t++) {
        if (t < 15) {
            bf16* base = (bf16*)smem + ((t + 1) & 1) * 16384;
            int k0 = (t + 1) * 64;
            #pragma unroll
            for (int it = 0; it < 4; it++) {
                int c = it * 256 + tid;
                int row = c >> 3, col = (c & 7) * 8;
                async_ld16(Xp + (size_t)(tile_m + row) * HID + k0 + col, &base[c * 8]);
                async_ld16(WT + (size_t)(tile_n + row) * HID + k0 + col, &base[8192 + c * 8]);
            }
        }
        const bf16* As = (const bf16*)smem + (t & 1) * 16384;
        const bf16* Bs = As + 8192;
        #pragma unroll
        for (int ks = 0; ks < 64; ks += 32) {
            bf16x8 a[4], b[4];
            for (int i = 0; i < 4; i++)
                a[i] = *reinterpret_cast<const bf16x8*>(&As[(wm + i * 16 + lm) * 64 + ks + quad * 8]);
            for (int j = 0; j < 4; j++)
                b[j] = *reinterpret_cast<const bf16x8*>(&Bs[(wn + j * 16 + lm) * 64 + ks + quad * 8]);
            for (int i = 0; i < 4; i++)
                for (int j = 0; j < 4; j++)
                    acc[i][j] = mfma16(a[i], b[j], acc[i][j]);
        }
        __syncthreads();   // stage t+1 landed; all waves done reading buf[t]
    }

    int which = tile_n >> 10;                 // 0=q,1=k,2=v (wave-uniform)
    int hc_base = (tile_n + wn) & 1023;       // multiple of 64
    int h = hc_base >> 6;
    const float* bias = (which == 0) ? bq : (which == 1) ? bk : bv;
    bf16* ep = (bf16*)smem + wave * (64 * 72);   // overlay; loop-final sync retired reads

    if (which < 2) {
        #pragma unroll
        for (int i = 0; i < 4; i++)
            #pragma unroll
            for (int j = 0; j < 4; j++) {
                float bsv = bias[hc_base + j * 16 + lm];
                #pragma unroll
                for (int r = 0; r < 4; r++) {
                    float val = acc[i][j][r] + bsv;
                    if (which == 0) val *= 0.125f;
                    ep[(i * 16 + quad * 4 + r) * 72 + j * 16 + lm] = (bf16)val;
                }
            }
        __builtin_amdgcn_wave_barrier();
        int s_glob = tile_m + wm + lane;
        int b_ = s_glob >> 12, s = s_glob & 4095;
        bf16* dstb = ((which == 0) ? qo : ko) + ((size_t)((b_ * NH + h) * SEQ + s)) * HD;
        #pragma unroll
        for (int c = 0; c < 8; c++)
            *reinterpret_cast<uint4*>(dstb + c * 8) =
                *reinterpret_cast<const uint4*>(ep + lane * 72 + c * 8);
    } else {
        #pragma unroll
        for (int i = 0; i < 4; i++)
            #pragma unroll
            for (int j = 0; j < 4; j++) {
                float bsv = bias[hc_base + j * 16 + lm];
                #pragma unroll
                for (int r = 0; r < 4; r++) {
                    float val = acc[i][j][r] + bsv;
                    ep[(j * 16 + lm) * 72 + i * 16 + quad * 4 + r] = (bf16)val;
                }
            }
        __builtin_amdgcn_wave_barrier();
        int s_base = tile_m + wm;
        int b_ = s_base >> 12, s0 = s_base & 4095;
        bf16* dstb = vt + ((size_t)((b_ * NH + h) * HD + lane)) * SEQ + s0;
        #pragma unroll
        for (int c = 0; c < 8; c++)
            *reinterpret_cast<uint4*>(dstb + c * 8) =
                *reinterpret_cast<const uint4*>(ep + lane * 72 + c * 8);
    }
}

// ---------------- attention ----------------
// Round-9 kernel verbatim (106.6us best): in-register P transpose, 32KB LDS,
// DMA-staged K with counted vmcnt, fullmode-first. setprio REVERTED (r10:
// +5% regression -- middle-mode waves are barrier-coupled per chunk via the
// staging s_barrier, so boosting one wave delays the cooperative stage; m190).
__global__ __launch_bounds__(256, 2) void attn_kernel(const bf16* __restrict__ q,
                                                      const bf16* __restrict__ kk,
                                                      const bf16* __restrict__ vt,
                                                      const float* __restrict__ bandT,
                                                      const float* __restrict__ fromm,
                                                      const float* __restrict__ tom,
                                                      const float* __restrict__ blocked,
                                                      const int* __restrict__ rand_attn,
                                                      const int* __restrict__ flags,
                                                      bf16* __restrict__ attn) {
    // [0,32768): K staging, 2 buffers x (2 blocks x 4096 elems).
    // Fullmode: combine overlay (ctxL 16KB + mL/lL 512B) -- staging unused there.
    __shared__ __align__(16) char smem[32768];
    bf16* sK = (bf16*)smem;

    int tid = threadIdx.x, wave = tid >> 6, lane = tid & 63;
    int quad = lane >> 4, lm = lane & 15;
    int sw = lm & 7;                        // K-swizzle row key ((f*16+lm)&7 == lm&7)
    int bh = blockIdx.x;
    int b = bh >> 4, h = bh & 15;
    size_t bh_base = (size_t)bh * SEQ * HD;
    int x = blockIdx.y;
    bool fullmode = (x < 8);
    int l, sub;
    if (fullmode) { l = (x >> 2) ? (NB - 1) : 0; sub = x & 3; }
    else          { l = x - 7;                   sub = wave;  }

    bool do_to = flags[b] != 0;          // to_mask has non-ones
    bool do_bl = flags[BB + b] != 0;     // blocked has non-ones
    bool do_bd = flags[2 * BB + b] != 0; // band has non-ones

    // key-block list (middle mode), packed: kbp = 8 x 6-bit block ids (byte lanes),
    // typ_p = 8 x 4-bit types. type: 0=to_mask, 1..3=band(t), 4=rand, 5=pad.
    unsigned long long kbp = 0ull;
    unsigned int typ_p = 0u;
    if (!fullmode) {
        int base;
        if (l == 1) {
            kbp = (1ull << 8) | (2ull << 16) | ((unsigned long long)(NB - 1) << 24);
            base = 4;
        } else if (l == NB - 2) {
            kbp = ((unsigned long long)(NB - 3) << 8) | ((unsigned long long)(NB - 2) << 16) |
                  ((unsigned long long)(NB - 1) << 24);
            base = 4;
        } else {
            kbp = ((unsigned long long)(l - 1) << 8) | ((unsigned long long)l << 16) |
                  ((unsigned long long)(l + 1) << 24) | ((unsigned long long)(NB - 1) << 32);
            typ_p = (1u << 4) | (2u << 8) | (3u << 12);
            base = 5;
        }
        const int* ra = rand_attn + ((size_t)(b * NH + h) * (NB - 2) + (l - 1)) * NR;
        #pragma unroll
        for (int r = 0; r < NR; r++) {
            int rv = __builtin_amdgcn_readfirstlane(ra[r]);
            kbp   |= (unsigned long long)(rv & 63) << ((base + r) * 8);
            typ_p |= 4u << ((base + r) * 4);
        }
        for (int i = base + NR; i < 8; i++) typ_p |= 5u << (i * 4);   // pads (kb=0, masked off)
    }

    // Q fragments + per-lane query mask (issued before staging so the c0 wait
    // retires them together with the prologue stage; latencies overlap).
    bf16x8 aq0 = *reinterpret_cast<const bf16x8*>(
        q + bh_base + (size_t)(l * BLK + sub * 16 + lm) * HD + quad * 8);
    bf16x8 aq1 = *reinterpret_cast<const bf16x8*>(
        q + bh_base + (size_t)(l * BLK + sub * 16 + lm) * HD + 32 + quad * 8);
    float mq = blocked[((size_t)b * NB + l) * BLK + sub * 16 + lm];

    if (!fullmode) {
        MEMFENCE;
        int a0 = (int)((kbp >> 0) & 63),  a1 = (int)((kbp >> 8) & 63);
        int b0 = (int)((kbp >> 16) & 63), b1 = (int)((kbp >> 24) & 63);
        stage_k2(kk + bh_base, sK + 0,    a0, a1, tid);
        stage_k2(kk + bh_base, sK + 8192, b0, b1, tid);
        MEMFENCE;
    }

    floatx4 ctx[4] = {};        // O^T: d=dj*16+quad*4+r, query=lm
    float mrun = -1e30f, lrun = 0.f;   // lrun: PER-LANE partial (reduced at end)

    int sbase = ((quad & 1) << 5) + lm;   // source lane pair base for P shuffle
    int fhi = quad >> 1;                  // f-register select for P shuffle

    int nch = fullmode ? 8 : 4;
    for (int ch = 0; ch < nch; ch++) {
        int i0 = ch * 2, i1 = i0 + 1;
        int kb0, kb1, ty0, ty1;
        if (fullmode) {
            kb0 = __builtin_amdgcn_readfirstlane(wave * 16 + i0);
            kb1 = kb0 + 1;
            ty0 = 0; ty1 = 0;
        } else {
            kb0 = __builtin_amdgcn_readfirstlane((int)((kbp >> (i0 * 8)) & 63));
            kb1 = __builtin_amdgcn_readfirstlane((int)((kbp >> (i1 * 8)) & 63));
            ty0 = (int)((typ_p >> (i0 * 4)) & 15);
            ty1 = (int)((typ_p >> (i1 * 4)) & 15);
        }

        // ---- vf0 issue FIRST (addresses independent of K) ----
        const bf16* v0p = vt + bh_base + (size_t)kb0 * BLK;
        bf16x8 vf0[4][2];
        #pragma unroll
        for (int dj = 0; dj < 4; dj++) {
            vf0[dj][0] = *reinterpret_cast<const bf16x8*>(v0p + (size_t)(dj * 16 + lm) * SEQ + quad * 8);
            vf0[dj][1] = *reinterpret_cast<const bf16x8*>(v0p + (size_t)(dj * 16 + lm) * SEQ + 32 + quad * 8);
        }
        MEMFENCE;

        // ---- scores: S^T = K * Q^T; sc[u][f][r] = S^T[key=f*16+quad*4+r][q=lm] ----
        floatx4 sc[2][4];
        if (!fullmode) {
            // own stage (issued last chunk / prologue) retired; vf0 kept in flight
            if (ch < 3) asm volatile("s_waitcnt vmcnt(8)" ::: "memory");
            else        asm volatile("s_waitcnt vmcnt(16)" ::: "memory");  // stage(8) only
            __builtin_amdgcn_s_barrier();
            const bf16* kbuf = sK + (ch & 1) * 8192;
            #pragma unroll
            for (int u = 0; u < 2; u++) {
                bf16x8 ka[4], kb_[4];
                #pragma unroll
                for (int f = 0; f < 4; f++) {
                    int rowb = (f * 16 + lm) * 64;
                    ka[f]  = *reinterpret_cast<const bf16x8*>(
                        kbuf + u * 4096 + rowb + ((quad ^ sw) << 3));
                    kb_[f] = *reinterpret_cast<const bf16x8*>(
                        kbuf + u * 4096 + rowb + (((quad | 4) ^ sw) << 3));
                }
                #pragma unroll
                for (int f = 0; f < 4; f++) {
                    floatx4 z = {0.f, 0.f, 0.f, 0.f};
                    z = mfma16(ka[f], aq0, z);
                    z = mfma16(kb_[f], aq1, z);
                    sc[u][f] = z;
                }
            }
        } else {
            const bf16* k0p = kk + bh_base + (size_t)kb0 * (BLK * HD);
            const bf16* k1p = kk + bh_base + (size_t)kb1 * (BLK * HD);
            bf16x8 kfa[2][4], kfb[2][4];
            #pragma unroll
            for (int f = 0; f < 4; f++) {
                kfa[0][f] = *reinterpret_cast<const bf16x8*>(k0p + (f * 16 + lm) * HD + quad * 8);
                kfb[0][f] = *reinterpret_cast<const bf16x8*>(k0p + (f * 16 + lm) * HD + 32 + quad * 8);
                kfa[1][f] = *reinterpret_cast<const bf16x8*>(k1p + (f * 16 + lm) * HD + quad * 8);
                kfb[1][f] = *reinterpret_cast<const bf16x8*>(k1p + (f * 16 + lm) * HD + 32 + quad * 8);
            }
            #pragma unroll
            for (int u = 0; u < 2; u++)
                #pragma unroll
                for (int f = 0; f < 4; f++) {
                    floatx4 z = {0.f, 0.f, 0.f, 0.f};
                    z = mfma16(kfa[u][f], aq0, z);
                    z = mfma16(kfb[u][f], aq1, z);
                    sc[u][f] = z;
                }
        }

        // ---- vf1 issue (after QK so K frags are dead; ~600cy before PV1 use) ----
        const bf16* v1p = vt + bh_base + (size_t)kb1 * BLK;
        bf16x8 vf1[4][2];
        #pragma unroll
        for (int dj = 0; dj < 4; dj++) {
            vf1[dj][0] = *reinterpret_cast<const bf16x8*>(v1p + (size_t)(dj * 16 + lm) * SEQ + quad * 8);
            vf1[dj][1] = *reinterpret_cast<const bf16x8*>(v1p + (size_t)(dj * 16 + lm) * SEQ + 32 + quad * 8);
        }
        MEMFENCE;

        // ---- masks (key = f*16+quad*4+r, query = lm); skipped when mask all-ones ----
        {
            int kbs[2] = {kb0, kb1};
            int tys[2] = {ty0, ty1};
            #pragma unroll
            for (int u = 0; u < 2; u++) {
                int kb = kbs[u], typ = tys[u];
                if (typ == 0) {
                    if (do_to) {
                        #pragma unroll
                        for (int f = 0; f < 4; f++) {
                            float4 t4 = *reinterpret_cast<const float4*>(
                                tom + (size_t)b * SEQ + kb * BLK + f * 16 + quad * 4);
                            sc[u][f][0] += (1.f - t4.x) * PENV;
                            sc[u][f][1] += (1.f - t4.y) * PENV;
                            sc[u][f][2] += (1.f - t4.z) * PENV;
                            sc[u][f][3] += (1.f - t4.w) * PENV;
                        }
                    }
                } else if (typ == 4) {
                    if (do_bl) {
                        #pragma unroll
                        for (int f = 0; f < 4; f++) {
                            float4 t4 = *reinterpret_cast<const float4*>(
                                blocked + ((size_t)b * NB + kb) * BLK + f * 16 + quad * 4);
                            sc[u][f][0] += (1.f - mq * t4.x) * PENV;
                            sc[u][f][1] += (1.f - mq * t4.y) * PENV;
                            sc[u][f][2] += (1.f - mq * t4.z) * PENV;
                            sc[u][f][3] += (1.f - mq * t4.w) * PENV;
                        }
                    }
                } else if (typ != 5) {
                    if (do_bd) {
                        int t = typ - 1;
                        const float* bp = bandT + ((size_t)(b * (NB - 4) + (l - 2)) * 192 + t * 64) * BLK;
                        #pragma unroll
                        for (int f = 0; f < 4; f++)
                            #pragma unroll
                            for (int r = 0; r < 4; r++) {
                                float bm = bp[(size_t)(f * 16 + quad * 4 + r) * BLK + sub * 16 + lm];
                                sc[u][f][r] += (1.f - bm) * PENV;
                            }
                    }
                } else {
                    #pragma unroll
                    for (int f = 0; f < 4; f++)
                        #pragma unroll
                        for (int r = 0; r < 4; r++) sc[u][f][r] += PENV;
                }
            }
        }

        // ---- softmax: chunk max via 3 PARALLEL shuffles (one DS latency) ----
        float mx = -1e30f;
        #pragma unroll
        for (int u = 0; u < 2; u++)
            #pragma unroll
            for (int f = 0; f < 4; f++)
                #pragma unroll
                for (int r = 0; r < 4; r++) mx = fmaxf(mx, sc[u][f][r]);
        float a16 = __shfl_xor(mx, 16, 64);
        float a32 = __shfl_xor(mx, 32, 64);
        float a48 = __shfl_xor(mx, 48, 64);
        mx = fmaxf(fmaxf(mx, a16), fmaxf(a32, a48));
        float mnew = fmaxf(mrun, mx);
        float scale = __expf(mrun - mnew);
        #pragma unroll
        for (int dj = 0; dj < 4; dj++) ctx[dj] *= scale;
        mrun = mnew;

        // ---- exp -> packed bf16 pairs (in register); per-lane partial row-sum ----
        float rs = 0.f;
        uint2 pk[2][4];
        #pragma unroll
        for (int u = 0; u < 2; u++)
            #pragma unroll
            for (int f = 0; f < 4; f++) {
                float p0 = __expf(sc[u][f][0] - mnew);
                float p1 = __expf(sc[u][f][1] - mnew);
                float p2 = __expf(sc[u][f][2] - mnew);
                float p3 = __expf(sc[u][f][3] - mnew);
                rs += (p0 + p1) + (p2 + p3);
                union { bf16 hh[4]; uint2 u2; } pu;
                pu.hh[0] = (bf16)p0; pu.hh[1] = (bf16)p1;
                pu.hh[2] = (bf16)p2; pu.hh[3] = (bf16)p3;
                pk[u][f] = pu.u2;
            }
        lrun = lrun * scale + rs;          // per-lane partial; reduced once at end

        // ---- in-register P transpose: sc layout -> PV B-operand layout ----
        bf16x8 pb[2][2];
        #pragma unroll
        for (int u = 0; u < 2; u++) {
            unsigned g0x[4], g0y[4], g1x[4], g1y[4];
            #pragma unroll
            for (int f = 0; f < 4; f++) {
                g0x[f] = (unsigned)__shfl((int)pk[u][f].x, sbase, 64);
                g0y[f] = (unsigned)__shfl((int)pk[u][f].y, sbase, 64);
                g1x[f] = (unsigned)__shfl((int)pk[u][f].x, sbase + 16, 64);
                g1y[f] = (unsigned)__shfl((int)pk[u][f].y, sbase + 16, 64);
            }
            union { unsigned v[4]; bf16x8 hv; } lo, hi;
            lo.v[0] = fhi ? g0x[1] : g0x[0];
            lo.v[1] = fhi ? g0y[1] : g0y[0];
            lo.v[2] = fhi ? g1x[1] : g1x[0];
            lo.v[3] = fhi ? g1y[1] : g1y[0];
            hi.v[0] = fhi ? g0x[3] : g0x[2];
            hi.v[1] = fhi ? g0y[3] : g0y[2];
            hi.v[2] = fhi ? g1x[3] : g1x[2];
            hi.v[3] = fhi ? g1y[3] : g1y[2];
            pb[u][0] = lo.hv;
            pb[u][1] = hi.hv;
        }

        // ---- stage chunk ch+1's K (ISSUED LAST so PV waits never drain it) ----
        if (!fullmode && ch >= 1 && ch + 1 < 4) {
            int na = __builtin_amdgcn_readfirstlane((int)((kbp >> ((ch + 1) * 16)) & 63));
            int nb = __builtin_amdgcn_readfirstlane((int)((kbp >> ((ch + 1) * 16 + 8)) & 63));
            stage_k2(kk + bh_base, sK + ((ch + 1) & 1) * 8192, na, nb, tid);
            MEMFENCE;
        }

        // ---- PV block 0 (auto-wait vmcnt keeps vf1 + staged K in flight) ----
        #pragma unroll
        for (int dj = 0; dj < 4; dj++) {
            ctx[dj] = mfma16(vf0[dj][0], pb[0][0], ctx[dj]);
            ctx[dj] = mfma16(vf0[dj][1], pb[0][1], ctx[dj]);
        }
        // ---- PV block 1 (auto-wait keeps staged K in flight) ----
        #pragma unroll
        for (int dj = 0; dj < 4; dj++) {
            ctx[dj] = mfma16(vf1[dj][0], pb[1][0], ctx[dj]);
            ctx[dj] = mfma16(vf1[dj][1], pb[1][1], ctx[dj]);
        }
    }

    // ---- deferred l-sum reduce: 3 parallel shuffles, once per kernel ----
    {
        float b16 = __shfl_xor(lrun, 16, 64);
        float b32 = __shfl_xor(lrun, 32, 64);
        float b48 = __shfl_xor(lrun, 48, 64);
        lrun = (lrun + b16) + (b32 + b48);
    }

    if (!fullmode) {
        // per-lane finalize: query = lm
        int sq = l * BLK + sub * 16 + lm;
        float w = (1.f / lrun) * fromm[(size_t)b * SEQ + sq];
        bf16* dst = attn + ((size_t)(b * SEQ + sq)) * HID + h * HD;
        #pragma unroll
        for (int dj = 0; dj < 4; dj++) {
            union { bf16 hh[4]; uint2 u2; } o;
            #pragma unroll
            for (int r = 0; r < 4; r++) o.hh[r] = (bf16)(ctx[dj][r] * w);
            *reinterpret_cast<uint2*>(dst + dj * 16 + quad * 4) = o.u2;
        }
    } else {
        // cross-wave combine (4 partials over the same 16 queries)
        float* ctxL = (float*)smem;                    // [wave][d=64][q=16] (staging region, free)
        float* mL   = (float*)(smem + 16384);          // [wave][16]
        float* lL   = (float*)(smem + 16640);          // [wave][16]
        __syncthreads();
        #pragma unroll
        for (int dj = 0; dj < 4; dj++)
            #pragma unroll
            for (int r = 0; r < 4; r++)
                ctxL[wave * 1024 + (dj * 16 + quad * 4 + r) * 16 + lm] = ctx[dj][r];
        if (quad == 0) { mL[wave * 16 + lm] = mrun; lL[wave * 16 + lm] = lrun; }
        __syncthreads();
        int qq = tid & 15, dbase = (tid >> 4) * 4;
        float M = -1e30f;
        for (int w = 0; w < 4; w++) M = fmaxf(M, mL[w * 16 + qq]);
        float e[4], Lt = 0.f;
        for (int w = 0; w < 4; w++) { e[w] = __expf(mL[w * 16 + qq] - M); Lt += lL[w * 16 + qq] * e[w]; }
        int sq = l * BLK + sub * 16 + qq;
        float wgt = (1.f / Lt) * fromm[(size_t)b * SEQ + sq];
        union { bf16 hh[4]; uint2 u2; } o;
        #pragma unroll
        for (int dd = 0; dd < 4; dd++) {
            float acc = 0.f;
            for (int w = 0; w < 4; w++) acc += ctxL[w * 1024 + (dbase + dd) * 16 + qq] * e[w];
            o.hh[dd] = (bf16)(acc * wgt);
        }
        *reinterpret_cast<uint2*>(attn + ((size_t)(b * SEQ + sq)) * HID + h * HD + dbase) = o.u2;
    }
}

// ---------------- GEMM2: output projection ----------------
// 2-phase double-buffered K-pipeline (measured -13us in r10).
__global__ __launch_bounds__(256) void gemm_out(const bf16* __restrict__ A,
                                                const bf16* __restrict__ WoT,
                                                const float* __restrict__ bo,
                                                float* __restrict__ out) {
    __shared__ __align__(16) char smem[65536];   // 2 x (As 16KB + Bs 16KB)
    int tid = threadIdx.x;
    int wave = tid >> 6, lane = tid & 63;
    int quad = lane >> 4, lm = lane & 15;
    int id = blockIdx.x;
    int xcd = id & 7, slot = id >> 3;
    int tile_m = (xcd * 8 + (slot & 7)) * 128;
    int tile_n = (slot >> 3) * 128;
    int wm = (wave & 1) * 64, wn = (wave >> 1) * 64;

    floatx4 acc[4][4] = {};

    // prologue: stage tile 0 into buffer 0
    {
        bf16* base = (bf16*)smem;
        #pragma unroll
        for (int it = 0; it < 4; it++) {
            int c = it * 256 + tid;
            int row = c >> 3, col = (c & 7) * 8;
            async_ld16(A + (size_t)(tile_m + row) * HID + col, &base[c * 8]);
            async_ld16(WoT + (size_t)(tile_n + row) * HID + col, &base[8192 + c * 8]);
        }
    }
    __syncthreads();   // buf0 landed

    for (int t = 0; t < 16; t++) {
        // stage tile t+1 into the other buffer (in flight during compute)
        if (t < 15) {
            bf16* base = (bf16*)smem + ((t + 1) & 1) * 16384;
            int k0 = (t + 1) * 64;
            #pragma unroll
            for (int it = 0; it < 4; it++) {
                int c = it * 256 + tid;
                int row = c >> 3, col = (c & 7) * 8;
                async_ld16(A + (size_t)(tile_m + row) * HID + k0 + col, &base[c * 8]);
                async_ld16(WoT + (size_t)(tile_n + row) * HID + k0 + col, &base[8192 + c * 8]);
            }
        }
        const bf16* As = (const bf16*)smem + (t & 1) * 16384;
        const bf16* Bs = As + 8192;
        #pragma unroll
        for (int ks = 0; ks < 64; ks += 32) {
            bf16x8 a[4], b[4];
            for (int i = 0; i < 4; i++)
                a[i] = *reinterpret_cast<const bf16x8*>(&As[(wm + i * 16 + lm) * 64 + ks + quad * 8]);
            for (int j = 0; j < 4; j++)
                b[j] = *reinterpret_cast<const bf16x8*>(&Bs[(wn + j * 16 + lm) * 64 + ks + quad * 8]);
            for (int i = 0; i < 4; i++)
                for (int j = 0; j < 4; j++)
                    acc[i][j] = mfma16(a[i], b[j], acc[i][j]);
        }
        __syncthreads();   // stage t+1 landed; all waves done reading buf[t]
    }

    for (int i = 0; i < 4; i++) {
        for (int j = 0; j < 4; j++) {
            int nn = tile_n + wn + j * 16 + lm;
            float bsv = bo[nn];
            for (int r = 0; r < 4; r++) {
                int mm = tile_m + wm + i * 16 + quad * 4 + r;
                int b_ = mm >> 12, s = mm & 4095;
                if (s < LQ)
                    out[((size_t)(b_ * LQ + s)) * HID + nn] = acc[i][j][r] + bsv;
            }
        }
    }
}

// ---------------- launcher ----------------
extern "C" void kernel_launch(void* const* d_in, const int* in_sizes, int n_in,
                              void* d_out, int out_size, void* d_ws, size_t ws_size,
                              hipStream_t stream) {
    const float* X       = (const float*)d_in[0];
    const float* Wq      = (const float*)d_in[1];
    const float* bq      = (const float*)d_in[2];
    const float* Wk      = (const float*)d_in[3];
    const float* bk      = (const float*)d_in[4];
    const float* Wv      = (const float*)d_in[5];
    const float* bv      = (const float*)d_in[6];
    const float* Wo      = (const float*)d_in[7];
    const float* bo      = (const float*)d_in[8];
    const float* band    = (const float*)d_in[9];
    const float* fromm   = (const float*)d_in[10];
    const float* tom     = (const float*)d_in[11];
    const float* blocked = (const float*)d_in[12];
    const int*   randa   = (const int*)d_in[13];
    float* out = (float*)d_out;

    char* ws = (char*)d_ws;
    bf16* Xp    = (bf16*)(ws + 0);              // 16,777,216 B (reused as attn)
    bf16* WqkvT = (bf16*)(ws + 16777216);       //  6,291,456 B (reused as bandT+flags after gemm_qkv)
    bf16* WoT   = (bf16*)(ws + 23068672);       //  2,097,152 B
    bf16* qb    = (bf16*)(ws + 25165824);       // 16,777,216 B
    bf16* kb    = (bf16*)(ws + 41943040);       // 16,777,216 B
    bf16* vtb   = (bf16*)(ws + 58720256);       // 16,777,216 B (d-major V)
    bf16* attnb = Xp;                           // Xp dead after gemm_qkv
    float* bandT = (float*)WqkvT;               // 5,898,240 B, alive only during attn
    int* flagsp = (int*)(ws + 16777216 + 5898240);  // 24 B, inside dead WqkvT tail

    cast_pad_x<<<dim3(8192), dim3(256), 0, stream>>>(X, Xp);
    transpose_w<<<dim3(16, 16, 4), dim3(64, 4), 0, stream>>>(Wq, Wk, Wv, Wo, WqkvT, WoT);
    gemm_qkv<<<dim3(1536), dim3(256), 0, stream>>>(Xp, WqkvT, bq, bk, bv, qb, kb, vtb);
    transpose_band<<<dim3(3, NB - 4, BB), dim3(64, 4), 0, stream>>>(band, bandT);
    hipMemsetAsync(flagsp, 0, 3 * BB * sizeof(int), stream);
    mask_viol<<<dim3(240, 3, BB), dim3(256), 0, stream>>>(tom, blocked, band, flagsp);
    attn_kernel<<<dim3(BB * NH, 70), dim3(256), 0, stream>>>(qb, kb, vtb, bandT, fromm, tom,
                                                             blocked, randa, flagsp, attnb);
    gemm_out<<<dim3(512), dim3(256), 0, stream>>>(attnb, WoT, bo, out);
}